// Round 5
// baseline (656.513 us; speedup 1.0000x reference)
//
#include <hip/hip_runtime.h>
#include <hip/hip_bf16.h>

typedef __hip_bfloat16 bf16;
typedef __attribute__((ext_vector_type(8))) short short8;
typedef __attribute__((ext_vector_type(4))) float f32x4;

#define NN 2048
#define EE 4096
#define LL 49
#define LRR 16
#define NYY 3
#define CC 128
#define HH 128

#define K1P 2432   // 2401 padded to x64 (BT1 K)
#define K2P 2496   // 2450 padded to x64 (BT2 K)

__device__ __forceinline__ float siluf(float v) { return v * (1.0f / (1.0f + __expf(-v))); }
__device__ __forceinline__ bf16 f2b(float v) { return __float2bfloat16(v); }
__device__ __forceinline__ float getc(float4 v, int i) {
  return i == 0 ? v.x : i == 1 ? v.y : i == 2 ? v.z : v.w;
}

// ---------------- weight convert + transpose: out[n*Kp+k] = bf16(in[k*N+n]), zero-pad k>=K ----------------
struct TJob { const float* in; bf16* out; int K, N, Kp; };
struct TJobs { TJob j[6]; };

__global__ __launch_bounds__(256) void transpose_cvt_kernel(TJobs jobs) {
  TJob jb = jobs.j[blockIdx.y];
  int i = blockIdx.x * 256 + threadIdx.x;
  if (i < jb.N * jb.Kp) {
    int n = i / jb.Kp, k = i - n * jb.Kp;
    jb.out[i] = (k < jb.K) ? f2b(jb.in[(long)k * jb.N + n]) : f2b(0.f);
  }
}

// ---------------- CG weight prep: BT1[32][K1P], BT2[64][K2P] (transposed, bf16, zero-padded) ----------------
__global__ __launch_bounds__(256) void cg_prep_kernel(
    const float* __restrict__ Wcg1, const float* __restrict__ Wcg21,
    const float* __restrict__ Wcg22, bf16* __restrict__ BT1, bf16* __restrict__ BT2) {
  int i = blockIdx.x * 256 + threadIdx.x;
  if (blockIdx.y == 0) {
    if (i < 32 * K1P) {
      int o = i / K1P, k = i - o * K1P;
      float v = (o < 25 && k < 2401) ? Wcg1[k * 25 + o] : 0.f;
      BT1[i] = f2b(v);
    }
  } else {
    if (i < 64 * K2P) {
      int o = i / K2P, k = i - o * K2P;
      float v = 0.f;
      if (o < 49) {
        if (k < 1225) v = Wcg21[k * 49 + o];
        else if (k < 2450) v = Wcg22[(k - 1225) * 49 + o];
      }
      BT2[i] = f2b(v);
    }
  }
}

// ---------------- per-node channel mean ----------------
__global__ __launch_bounds__(256) void node_mean_kernel(const float* __restrict__ x,
                                                        float* __restrict__ xmean) {
  int row = blockIdx.x * 4 + (threadIdx.x >> 6);
  int lane = threadIdx.x & 63;
  const float* p = x + (long)row * CC;
  float s = p[lane] + p[lane + 64];
  for (int off = 32; off > 0; off >>= 1) s += __shfl_down(s, off);
  if (lane == 0) xmean[row] = s * (1.0f / 128.0f);
}

// ---------------- cg1: mid[e][o] = (xm_e (x) ym_e) @ BT1^T, A generated on the fly ----------------
// 32 edges/block, M=32, N=32, K=K1P. grid 128 x 256 threads.
__global__ __launch_bounds__(256) void cg1_kernel(
    const float* __restrict__ xmean, const int* __restrict__ eidx,
    const bf16* __restrict__ BT1, float* __restrict__ mid) {
  __shared__ float sxm[32 * 49], sym[32 * 49];
  __shared__ bf16 As[32 * 64];
  __shared__ bf16 Bs[32 * 64];
  __shared__ int se[32], de[32];
  const int tid = threadIdx.x, w = tid >> 6, lane = tid & 63;
  const int lm = lane & 15, q = lane >> 4;
  const int e0 = blockIdx.x * 32;
  if (tid < 32) { se[tid] = eidx[e0 + tid]; de[tid] = eidx[EE + e0 + tid]; }
  __syncthreads();
  for (int i = tid; i < 32 * 49; i += 256) {
    int m = i / 49, l = i - m * 49;
    sxm[i] = xmean[se[m] * 49 + l];
    sym[i] = xmean[de[m] * 49 + l];
  }
  const int mi = w >> 1, ni = w & 1;
  f32x4 acc = (f32x4){0.f, 0.f, 0.f, 0.f};
  for (int k0 = 0; k0 < K1P; k0 += 64) {
    __syncthreads();
    // generate A tile: As[m][kk] = xm[m][i]*ym[m][j], k=k0+kk=i*49+j
    for (int idx = tid; idx < 2048; idx += 256) {
      int m = idx >> 6, kk = idx & 63;
      int k = k0 + kk;
      float v = 0.f;
      if (k < 2401) { int i = k / 49, j = k - i * 49; v = sxm[m * 49 + i] * sym[m * 49 + j]; }
      int k8 = kk >> 3;
      As[(m * 8 + (k8 ^ (m & 7))) * 8 + (kk & 7)] = f2b(v);
    }
    {  // stage B tile (1 uint4/thread)
      int n = tid >> 3, k8 = tid & 7;
      uint4 v = *(const uint4*)((const char*)BT1 + ((long)n * K1P + k0 + k8 * 8) * 2);
      *(uint4*)&Bs[(n * 8 + (k8 ^ (n & 7))) * 8] = v;
    }
    __syncthreads();
#pragma unroll
    for (int ks = 0; ks < 2; ++ks) {
      int am = mi * 16 + lm, bn = ni * 16 + lm;
      short8 af = *(const short8*)&As[(am * 8 + ((ks * 4 + q) ^ (am & 7))) * 8];
      short8 bfr = *(const short8*)&Bs[(bn * 8 + ((ks * 4 + q) ^ (bn & 7))) * 8];
      acc = __builtin_amdgcn_mfma_f32_16x16x32_bf16(af, bfr, acc, 0, 0, 0);
    }
  }
#pragma unroll
  for (int r = 0; r < 4; ++r)
    mid[(long)(e0 + mi * 16 + q * 4 + r) * 32 + ni * 16 + lm] = acc[r];
}

// ---------------- cg2: asum[e][o] = [xm (x) mid | ym (x) mid] @ BT2^T, A on the fly ----------------
// 32 edges/block, M=32, N=64, K=K2P. grid 128 x 256 threads.
__global__ __launch_bounds__(256) void cg2_kernel(
    const float* __restrict__ xmean, const float* __restrict__ mid,
    const int* __restrict__ eidx, const bf16* __restrict__ BT2,
    float* __restrict__ asum) {
  __shared__ float sxm[32 * 49], sym[32 * 49], smid[32 * 25];
  __shared__ bf16 As[32 * 64];
  __shared__ bf16 Bs[64 * 64];
  __shared__ int se[32], de[32];
  const int tid = threadIdx.x, w = tid >> 6, lane = tid & 63;
  const int lm = lane & 15, q = lane >> 4;
  const int e0 = blockIdx.x * 32;
  if (tid < 32) { se[tid] = eidx[e0 + tid]; de[tid] = eidx[EE + e0 + tid]; }
  __syncthreads();
  for (int i = tid; i < 32 * 49; i += 256) {
    int m = i / 49, l = i - m * 49;
    sxm[i] = xmean[se[m] * 49 + l];
    sym[i] = xmean[de[m] * 49 + l];
  }
  for (int i = tid; i < 32 * 25; i += 256) {
    int m = i / 25, l = i - m * 25;
    smid[i] = mid[(long)(e0 + m) * 32 + l];
  }
  const int ni = w;
  f32x4 acc[2];
  acc[0] = (f32x4){0.f, 0.f, 0.f, 0.f};
  acc[1] = (f32x4){0.f, 0.f, 0.f, 0.f};
  for (int k0 = 0; k0 < K2P; k0 += 64) {
    __syncthreads();
    for (int idx = tid; idx < 2048; idx += 256) {
      int m = idx >> 6, kk = idx & 63;
      int k = k0 + kk;
      float v = 0.f;
      if (k < 1225) {
        int i = k / 25, mm = k - i * 25;
        v = sxm[m * 49 + i] * smid[m * 25 + mm];
      } else if (k < 2450) {
        int kk2 = k - 1225;
        int i = kk2 / 25, mm = kk2 - i * 25;
        v = sym[m * 49 + i] * smid[m * 25 + mm];
      }
      int k8 = kk >> 3;
      As[(m * 8 + (k8 ^ (m & 7))) * 8 + (kk & 7)] = f2b(v);
    }
#pragma unroll
    for (int it = 0; it < 2; ++it) {  // stage B: 64 rows x 64 k
      int lc = it * 256 + tid;
      int n = lc >> 3, k8 = lc & 7;
      uint4 v = *(const uint4*)((const char*)BT2 + ((long)n * K2P + k0 + k8 * 8) * 2);
      *(uint4*)&Bs[(n * 8 + (k8 ^ (n & 7))) * 8] = v;
    }
    __syncthreads();
#pragma unroll
    for (int ks = 0; ks < 2; ++ks) {
      int bn = ni * 16 + lm;
      short8 bfr = *(const short8*)&Bs[(bn * 8 + ((ks * 4 + q) ^ (bn & 7))) * 8];
#pragma unroll
      for (int mi = 0; mi < 2; ++mi) {
        int am = mi * 16 + lm;
        short8 af = *(const short8*)&As[(am * 8 + ((ks * 4 + q) ^ (am & 7))) * 8];
        acc[mi] = __builtin_amdgcn_mfma_f32_16x16x32_bf16(af, bfr, acc[mi], 0, 0, 0);
      }
    }
  }
#pragma unroll
  for (int mi = 0; mi < 2; ++mi)
#pragma unroll
    for (int r = 0; r < 4; ++r)
      asum[(long)(e0 + mi * 16 + q * 4 + r) * 64 + ni * 16 + lm] = acc[mi][r];
}

// ---------------- feat build -> bf16 [8192][2112] (rows e, 4096+e), pad cols 2064..2111 = 0 ----------------
__global__ __launch_bounds__(256) void build_feat_kernel(
    const float* __restrict__ x, const float* __restrict__ x_glovec,
    const float* __restrict__ wig_node, const int* __restrict__ eidx,
    bf16* __restrict__ featst) {
  __shared__ float wig[256];
  __shared__ float xa[2048], xb[2048], tmp[2048];
  int e = blockIdx.x, tid = threadIdx.x;
  int s = eidx[e], d = eidx[EE + e];
  wig[tid] = wig_node[e * 256 + tid];
  if (tid < 48) {
    featst[(long)e * 2112 + 2064 + tid] = f2b(0.f);
    featst[(long)(EE + e) * 2112 + 2064 + tid] = f2b(0.f);
  }
  for (int i4 = tid; i4 < 512; i4 += 256) {
    int l = i4 >> 5, c4 = i4 & 31;
    *(float4*)&xa[l * 128 + c4 * 4] = *(const float4*)&x[((long)s * LL + l) * CC + c4 * 4];
    *(float4*)&xb[l * 128 + c4 * 4] = *(const float4*)&x[((long)d * LL + l) * CC + c4 * 4];
  }
  __syncthreads();
  for (int idx = tid; idx < 2048; idx += 256) {
    int i = idx >> 7, c = idx & 127;
    float a = 0.f;
#pragma unroll
    for (int j = 0; j < 16; ++j) a += wig[j * 16 + i] * xa[j * 128 + c];
    tmp[idx] = a;
    featst[(long)e * 2112 + i * 129 + c] = f2b(a);
  }
  __syncthreads();
  {
    int row = tid >> 4, t = tid & 15;
    float m = 0.f;
#pragma unroll
    for (int k = 0; k < 8; ++k) m += tmp[row * 128 + t + k * 16];
    m += __shfl_down(m, 8, 16);
    m += __shfl_down(m, 4, 16);
    m += __shfl_down(m, 2, 16);
    m += __shfl_down(m, 1, 16);
    if (t == 0)
      featst[(long)e * 2112 + row * 129 + 128] =
          f2b(m * (1.0f / 128.0f) * x_glovec[(long)d * 16 + row]);
  }
  __syncthreads();
  for (int idx = tid; idx < 2048; idx += 256) {
    int i = idx >> 7, c = idx & 127;
    float a = 0.f;
#pragma unroll
    for (int j = 0; j < 16; ++j) a += wig[j * 16 + i] * xb[j * 128 + c];
    tmp[idx] = a;
    featst[(long)(EE + e) * 2112 + i * 129 + c] = f2b(a);
  }
  __syncthreads();
  {
    int row = tid >> 4, t = tid & 15;
    float m = 0.f;
#pragma unroll
    for (int k = 0; k < 8; ++k) m += tmp[row * 128 + t + k * 16];
    m += __shfl_down(m, 8, 16);
    m += __shfl_down(m, 4, 16);
    m += __shfl_down(m, 2, 16);
    m += __shfl_down(m, 1, 16);
    if (t == 0)
      featst[(long)(EE + e) * 2112 + row * 129 + 128] =
          f2b(m * (1.0f / 128.0f) * x_glovec[(long)s * 16 + row]);
  }
}

// ---------------- fp32 tiled GEMM (only for tiny xe GEMM) ----------------
__global__ __launch_bounds__(256) void gemm_f32_silu(
    const float* __restrict__ A, const float* __restrict__ B,
    const float* __restrict__ bias, float* __restrict__ C, int M, int N, int K) {
  __shared__ float As[16][68];
  __shared__ float Bs[16][64];
  const int tid = threadIdx.x;
  const int bm = blockIdx.x * 64, bn = blockIdx.y * 64;
  const int tx = tid & 15, ty = tid >> 4;
  const int ar = tid >> 2, ak = (tid & 3) * 4;
  const int br = tid >> 4, bc = (tid & 15) * 4;
  float acc[4][4] = {};
  const float* Ap = A + (long)(bm + ar) * K + ak;
  const float* Bp = B + (long)br * N + bn + bc;
  for (int k0 = 0; k0 < K; k0 += 16) {
    const float4 av = *(const float4*)(Ap + k0);
    const float4 bv = *(const float4*)(Bp + (long)k0 * N);
    __syncthreads();
    As[ak + 0][ar] = av.x; As[ak + 1][ar] = av.y;
    As[ak + 2][ar] = av.z; As[ak + 3][ar] = av.w;
    *(float4*)&Bs[br][bc] = bv;
    __syncthreads();
#pragma unroll
    for (int k = 0; k < 16; ++k) {
      const float4 a = *(const float4*)&As[k][ty * 4];
      const float4 b = *(const float4*)&Bs[k][tx * 4];
      acc[0][0] += a.x * b.x; acc[0][1] += a.x * b.y; acc[0][2] += a.x * b.z; acc[0][3] += a.x * b.w;
      acc[1][0] += a.y * b.x; acc[1][1] += a.y * b.y; acc[1][2] += a.y * b.z; acc[1][3] += a.y * b.w;
      acc[2][0] += a.z * b.x; acc[2][1] += a.z * b.y; acc[2][2] += a.z * b.z; acc[2][3] += a.z * b.w;
      acc[3][0] += a.w * b.x; acc[3][1] += a.w * b.y; acc[3][2] += a.w * b.z; acc[3][3] += a.w * b.w;
    }
  }
#pragma unroll
  for (int i = 0; i < 4; ++i) {
    int row = bm + ty * 4 + i;
#pragma unroll
    for (int j = 0; j < 4; ++j) {
      int col = bn + tx * 4 + j;
      C[(long)row * N + col] = siluf(acc[i][j] + bias[col]);
    }
  }
}

// ---------------- bf16 MFMA GEMM: C = epi(A[MxK]bf16 @ BT[NxK]bf16^T + bias) ----------------
template <int BM, bool SILU, bool XE, bool OUT_BF16>
__global__ __launch_bounds__(256) void gemm_mfma(
    const bf16* __restrict__ A, const bf16* __restrict__ B0, const bf16* __restrict__ B1,
    const float* __restrict__ bias0, const float* __restrict__ bias1,
    const float* __restrict__ xe, void* __restrict__ Cout,
    int M, int N, int K, int half) {
  constexpr int MI = (BM + 31) / 32;
  __shared__ short As[BM * 64];
  __shared__ short Bs[128 * 64];
  const int tid = threadIdx.x;
  const int w = tid >> 6, lane = tid & 63;
  const int lm = lane & 15, q = lane >> 4;
  const int bm = blockIdx.x * BM, bn = blockIdx.y * 128;
  const int wm = (w & 1) * (BM / 2), wn = (w >> 1) * 64;
  const bf16* Bp = (bm < half) ? B0 : B1;
  const float* bias = (bm < half) ? bias0 : bias1;

  f32x4 acc[MI][4];
#pragma unroll
  for (int mi = 0; mi < MI; ++mi)
#pragma unroll
    for (int ni = 0; ni < 4; ++ni) acc[mi][ni] = (f32x4){0.f, 0.f, 0.f, 0.f};

  for (int k0 = 0; k0 < K; k0 += 64) {
    __syncthreads();
#pragma unroll
    for (int it = 0; it < BM / 32; ++it) {
      int lc = it * 256 + tid;
      int m = lc >> 3, k8 = lc & 7;
      uint4 v = *(const uint4*)((const char*)A + ((long)(bm + m) * K + k0 + k8 * 8) * 2);
      *(uint4*)&As[(m * 8 + (k8 ^ (m & 7))) * 8] = v;
    }
#pragma unroll
    for (int it = 0; it < 4; ++it) {
      int lc = it * 256 + tid;
      int n = lc >> 3, k8 = lc & 7;
      uint4 v = *(const uint4*)((const char*)Bp + ((long)(bn + n) * K + k0 + k8 * 8) * 2);
      *(uint4*)&Bs[(n * 8 + (k8 ^ (n & 7))) * 8] = v;
    }
    __syncthreads();
#pragma unroll
    for (int ks = 0; ks < 2; ++ks) {
      short8 af[MI], bfr[4];
#pragma unroll
      for (int mi = 0; mi < MI; ++mi) {
        int row = wm + mi * 16 + lm;
        af[mi] = *(const short8*)&As[row * 64 + ((ks * 4 + q) ^ (lm & 7)) * 8];
      }
#pragma unroll
      for (int ni = 0; ni < 4; ++ni) {
        int row = wn + ni * 16 + lm;
        bfr[ni] = *(const short8*)&Bs[row * 64 + ((ks * 4 + q) ^ (lm & 7)) * 8];
      }
#pragma unroll
      for (int mi = 0; mi < MI; ++mi)
#pragma unroll
        for (int ni = 0; ni < 4; ++ni)
          acc[mi][ni] = __builtin_amdgcn_mfma_f32_16x16x32_bf16(af[mi], bfr[ni], acc[mi][ni], 0, 0, 0);
    }
  }
#pragma unroll
  for (int mi = 0; mi < MI; ++mi) {
#pragma unroll
    for (int ni = 0; ni < 4; ++ni) {
      int col = bn + wn + ni * 16 + lm;
      float bcol = bias[col];
#pragma unroll
      for (int r = 0; r < 4; ++r) {
        int row = bm + wm + mi * 16 + q * 4 + r;
        float v = acc[mi][ni][r] + bcol;
        if (SILU) v = siluf(v);
        if (XE) v *= xe[(row / 3) * HH + col];
        if (OUT_BF16) ((bf16*)Cout)[(long)row * N + col] = f2b(v);
        else ((float*)Cout)[(long)row * N + col] = v;
      }
    }
  }
}

// ---------------- osum = silu(h1 @ Wn1b + b1) + silu(h2 @ Wn2b + b2): M=4096, N=2048, K=128 ----------------
__global__ __launch_bounds__(256) void gemm_osum(
    const bf16* __restrict__ A, const bf16* __restrict__ B0w, const bf16* __restrict__ B1w,
    const float* __restrict__ bias0, const float* __restrict__ bias1,
    float* __restrict__ osum) {
  __shared__ short As[128 * 64];
  __shared__ short Bs[128 * 64];
  const int tid = threadIdx.x;
  const int w = tid >> 6, lane = tid & 63;
  const int lm = lane & 15, q = lane >> 4;
  const int bm = blockIdx.x * 128, bn = blockIdx.y * 128;
  const int wm = (w & 1) * 64, wn = (w >> 1) * 64;
  f32x4 ov[4][4];
  f32x4 acc[4][4];
#pragma unroll
  for (int mi = 0; mi < 4; ++mi)
#pragma unroll
    for (int ni = 0; ni < 4; ++ni) acc[mi][ni] = (f32x4){0.f, 0.f, 0.f, 0.f};

#pragma unroll 1
  for (int src = 0; src < 2; ++src) {
    const bf16* Ap = A + (long)src * 4096 * 128;
    const bf16* Bp = src ? B1w : B0w;
#pragma unroll 1
    for (int k0 = 0; k0 < 128; k0 += 64) {
      __syncthreads();
#pragma unroll
      for (int it = 0; it < 4; ++it) {
        int lc = it * 256 + tid;
        int m = lc >> 3, k8 = lc & 7;
        uint4 v = *(const uint4*)((const char*)Ap + ((long)(bm + m) * 128 + k0 + k8 * 8) * 2);
        *(uint4*)&As[(m * 8 + (k8 ^ (m & 7))) * 8] = v;
      }
#pragma unroll
      for (int it = 0; it < 4; ++it) {
        int lc = it * 256 + tid;
        int n = lc >> 3, k8 = lc & 7;
        uint4 v = *(const uint4*)((const char*)Bp + ((long)(bn + n) * 128 + k0 + k8 * 8) * 2);
        *(uint4*)&Bs[(n * 8 + (k8 ^ (n & 7))) * 8] = v;
      }
      __syncthreads();
#pragma unroll
      for (int ks = 0; ks < 2; ++ks) {
        short8 af[4], bfr[4];
#pragma unroll
        for (int mi = 0; mi < 4; ++mi)
          af[mi] = *(const short8*)&As[(wm + mi * 16 + lm) * 64 + ((ks * 4 + q) ^ (lm & 7)) * 8];
#pragma unroll
        for (int ni = 0; ni < 4; ++ni)
          bfr[ni] = *(const short8*)&Bs[(wn + ni * 16 + lm) * 64 + ((ks * 4 + q) ^ (lm & 7)) * 8];
#pragma unroll
        for (int mi = 0; mi < 4; ++mi)
#pragma unroll
          for (int ni = 0; ni < 4; ++ni)
            acc[mi][ni] = __builtin_amdgcn_mfma_f32_16x16x32_bf16(af[mi], bfr[ni], acc[mi][ni], 0, 0, 0);
      }
    }
    if (src == 0) {
#pragma unroll
      for (int mi = 0; mi < 4; ++mi)
#pragma unroll
        for (int ni = 0; ni < 4; ++ni) {
          int col = bn + wn + ni * 16 + lm;
          float bc = bias0[col];
#pragma unroll
          for (int r = 0; r < 4; ++r) ov[mi][ni][r] = siluf(acc[mi][ni][r] + bc);
#pragma unroll
          for (int r = 0; r < 4; ++r) acc[mi][ni][r] = 0.f;
        }
    }
  }
#pragma unroll
  for (int mi = 0; mi < 4; ++mi)
#pragma unroll
    for (int ni = 0; ni < 4; ++ni) {
      int col = bn + wn + ni * 16 + lm;
      float bc = bias1[col];
#pragma unroll
      for (int r = 0; r < 4; ++r) {
        int row = bm + wm + mi * 16 + q * 4 + r;
        osum[(long)row * 2048 + col] = ov[mi][ni][r] + siluf(acc[mi][ni][r] + bc);
      }
    }
}

// ---------------- fused: sh = wig_node @ osum; z = 2(xs+xt)+asum+pad(sh); msg = wigner @ z ------------
// 512 threads / edge. Split-bf16 (hi/lo, 3 products) keeps fp32-equivalent accuracy.
__global__ __launch_bounds__(512, 4) void rotate_msg_fused_kernel(
    const float* __restrict__ x, const float* __restrict__ wigner,
    const int* __restrict__ eidx, const float* __restrict__ asum,
    const float* __restrict__ osum, const float* __restrict__ wig_node,
    bf16* __restrict__ msg) {
  __shared__ bf16 Ah[48 * 64], Al[48 * 64];        // wigner hi/lo, XOR-swizzled rows (12 KB)
  __shared__ bf16 zTh[128 * 64], zTl[128 * 64];    // z^T hi/lo, GEMM-B layout (32 KB)
  __shared__ float z[49 * 132];                    // fp32 z (25.9 KB)
  __shared__ float osum_s[16 * 128];               // (8 KB)
  __shared__ float wig[256];
  __shared__ float as_s[49];
  const int e = blockIdx.x, tid = threadIdx.x;
  const int s = eidx[e], d = eidx[EE + e];
  const int w = tid >> 6, lane = tid & 63;
  const int lm = lane & 15, q = lane >> 4;

  // ---- P1: stage everything (independent vector loads) ----
  if (tid < 49) as_s[tid] = asum[e * 64 + tid];
  if (tid >= 64 && tid < 128) {
    int i = tid - 64;
    *(float4*)&wig[i * 4] = *(const float4*)&wig_node[(long)e * 256 + i * 4];
  }
  *(float4*)&osum_s[tid * 4] = *(const float4*)&osum[(long)e * 2048 + tid * 4];
  for (int i = tid; i < 48 * 15; i += 512) {  // A zero-pad k in [49,64)
    int m = i / 15, k = 49 + (i - m * 15);
    int off = m * 64 + (((k >> 3) ^ (m & 7)) << 3) + (k & 7);
    Ah[off] = f2b(0.f); Al[off] = f2b(0.f);
  }
  for (int i4 = tid; i4 < 588; i4 += 512) {   // wigner -> Ah/Al (float4 loads)
    float4 v4 = *(const float4*)&wigner[(long)e * 2352 + i4 * 4];
    int i = i4 * 4;
    int m = i / 49, k = i - m * 49;
    float vv[4] = {v4.x, v4.y, v4.z, v4.w};
#pragma unroll
    for (int j = 0; j < 4; ++j) {
      bf16 h = f2b(vv[j]);
      bf16 l = f2b(vv[j] - __bfloat162float(h));
      int off = m * 64 + (((k >> 3) ^ (m & 7)) << 3) + (k & 7);
      Ah[off] = h; Al[off] = l;
      if (++k == 49) { k = 0; ++m; }
    }
  }
  __syncthreads();

  // ---- P2: z build (float4 writes, conflict-free), sh fused inline for rows l<16 ----
  {
    const float* xs = x + (long)s * (LL * CC);
    const float* xt = x + (long)d * (LL * CC);
    for (int i4 = tid; i4 < 49 * 32; i4 += 512) {
      int l = i4 >> 5, c4 = i4 & 31;
      float4 a = *(const float4*)&xs[l * 128 + c4 * 4];
      float4 b = *(const float4*)&xt[l * 128 + c4 * 4];
      float ad = as_s[l];
      float4 v;
      v.x = 2.f * (a.x + b.x) + ad;
      v.y = 2.f * (a.y + b.y) + ad;
      v.z = 2.f * (a.z + b.z) + ad;
      v.w = 2.f * (a.w + b.w) + ad;
      if (l < 16) {
#pragma unroll
        for (int j = 0; j < 16; ++j) {
          float wv = wig[l * 16 + j];                       // broadcast
          float4 o = *(const float4*)&osum_s[j * 128 + c4 * 4];
          v.x += wv * o.x; v.y += wv * o.y; v.z += wv * o.z; v.w += wv * o.w;
        }
      }
      *(float4*)&z[l * 132 + c4 * 4] = v;
    }
  }
  __syncthreads();

  // ---- P3: transpose via 4x float4 reads (conflict-free granule map) + 8B packed writes (2-way) ----
  {
    const int b0 = (tid & 15) * 4;
    const int c0 = (tid >> 4) * 4;
    float4 rv[4];
#pragma unroll
    for (int j = 0; j < 4; ++j)
      rv[j] = (b0 + j < 49) ? *(const float4*)&z[(b0 + j) * 132 + c0]
                            : (float4){0.f, 0.f, 0.f, 0.f};
#pragma unroll
    for (int i = 0; i < 4; ++i) {
      int c = c0 + i;
      union { bf16 b[4]; unsigned long long u; } hu, lu;
#pragma unroll
      for (int j = 0; j < 4; ++j) {
        float v = getc(rv[j], i);
        bf16 h = f2b(v);
        hu.b[j] = h;
        lu.b[j] = f2b(v - __bfloat162float(h));
      }
      int off = c * 64 + (((b0 >> 3) ^ (c & 7)) << 3) + (b0 & 7);
      *(unsigned long long*)&zTh[off] = hu.u;
      *(unsigned long long*)&zTl[off] = lu.u;
    }
  }
  __syncthreads();

  // ---- P4: MFMA (wave w -> n-tile w, m-tiles = NY taps) + store ----
  short8 ah[3][2], alo[3][2], bh[2], bl[2];
#pragma unroll
  for (int mi = 0; mi < 3; ++mi)
#pragma unroll
    for (int ks = 0; ks < 2; ++ks) {
      int off = (mi * 16 + lm) * 64 + (((ks * 4 + q) ^ (lm & 7)) << 3);
      ah[mi][ks] = *(const short8*)&Ah[off];
      alo[mi][ks] = *(const short8*)&Al[off];
    }
#pragma unroll
  for (int ks = 0; ks < 2; ++ks) {
    int off = (w * 16 + lm) * 64 + (((ks * 4 + q) ^ (lm & 7)) << 3);
    bh[ks] = *(const short8*)&zTh[off];
    bl[ks] = *(const short8*)&zTl[off];
  }
  f32x4 acc[3];
#pragma unroll
  for (int mi = 0; mi < 3; ++mi) acc[mi] = (f32x4){0.f, 0.f, 0.f, 0.f};
#pragma unroll
  for (int mi = 0; mi < 3; ++mi)
#pragma unroll
    for (int ks = 0; ks < 2; ++ks) {
      acc[mi] = __builtin_amdgcn_mfma_f32_16x16x32_bf16(ah[mi][ks], bh[ks], acc[mi], 0, 0, 0);
      acc[mi] = __builtin_amdgcn_mfma_f32_16x16x32_bf16(ah[mi][ks], bl[ks], acc[mi], 0, 0, 0);
      acc[mi] = __builtin_amdgcn_mfma_f32_16x16x32_bf16(alo[mi][ks], bh[ks], acc[mi], 0, 0, 0);
    }
  {
    int c = w * 16 + lm;
#pragma unroll
    for (int mi = 0; mi < 3; ++mi) {
      long base = ((long)e * 3 + mi) * 2048 + c;
#pragma unroll
      for (int r = 0; r < 4; ++r)
        msg[base + (q * 4 + r) * 128] = f2b(acc[mi][r]);
    }
  }
}

// ---------------- fused m2 GEMM + mean_ny + RotateInv, register-accumulated out ----------------
// 4 edges/block. oacc[b] += wv[b][nc] * mean_ny(silu(m2))[nc][c] accumulated over the nc loop.
__global__ __launch_bounds__(512) void m2out_kernel(
    const bf16* __restrict__ m1, const bf16* __restrict__ BTp2,
    const float* __restrict__ bp2, const float* __restrict__ wigner_inv,
    float* __restrict__ out) {
  __shared__ short As[2][16 * 64];     // 4 KB
  __shared__ short Bs[2][128 * 64];    // 32 KB (single-buffered; reg-prefetch hides L2)
  __shared__ float pbuf[16 * 132];     // 8.45 KB
  __shared__ float wvp[4][16 * 52];    // wigner_inv transposed, row-pad 52 (13 KB)
  const int tid = threadIdx.x;
  const int w = tid >> 6, lane = tid & 63;
  const int lm = lane & 15, q = lane >> 4;
  const int e0 = blockIdx.x * 4;
  const int ep = tid >> 7, cc = tid & 127;

  // stage A: 12 real rows of m1 -> 16 padded, swizzled per 64-k half
  if (tid < 256) {
    int n = tid >> 4, k8 = tid & 15;
    uint4 v = (uint4){0, 0, 0, 0};
    if (n < 12) v = *(const uint4*)((const char*)m1 + ((long)(e0 * 3 + n) * 128 + k8 * 8) * 2);
    *(uint4*)&As[k8 >> 3][(n * 8 + ((k8 & 7) ^ (n & 7))) * 8] = v;
  }
  // stage wigner_inv transposed: wvp[ep][rr*52 + b] = wigner_inv[e0+ep][b][rr]
  for (int i = tid; i < 3136; i += 512) {
    int ep2 = i / 784, r = i - ep2 * 784;
    int b = r >> 4, rr = r & 15;
    wvp[ep2][rr * 52 + b] = wigner_inv[(long)e0 * 784 + i];
  }

  float oacc[49];
#pragma unroll
  for (int b = 0; b < 49; ++b) oacc[b] = 0.f;

  // prefetch B chunk 0 into regs
  uint4 bv[4];
#pragma unroll
  for (int it = 0; it < 4; ++it) {
    int lc = it * 512 + tid;
    int n = lc >> 4, k8 = lc & 15;
    bv[it] = *(const uint4*)((const char*)BTp2 + ((long)n * 128 + k8 * 8) * 2);
  }

#pragma unroll 1
  for (int nc = 0; nc < 16; ++nc) {
    // write Bs from regs, then issue next chunk's loads (hide L2 latency under compute)
#pragma unroll
    for (int it = 0; it < 4; ++it) {
      int lc = it * 512 + tid;
      int n = lc >> 4, k8 = lc & 15;
      *(uint4*)&Bs[k8 >> 3][(n * 8 + ((k8 & 7) ^ (n & 7))) * 8] = bv[it];
    }
    if (nc < 15) {
#pragma unroll
      for (int it = 0; it < 4; ++it) {
        int lc = it * 512 + tid;
        int n = lc >> 4, k8 = lc & 15;
        bv[it] = *(const uint4*)((const char*)BTp2 + ((long)((nc + 1) * 128 + n) * 128 + k8 * 8) * 2);
      }
    }
    __syncthreads();  // Bs ready (also As/wvp on first iter)
    f32x4 acc = (f32x4){0.f, 0.f, 0.f, 0.f};
#pragma unroll
    for (int ks = 0; ks < 4; ++ks) {
      int kh = ks >> 1, ksl = ks & 1;
      short8 af = *(const short8*)&As[kh][(lm * 8 + ((ksl * 4 + q) ^ (lm & 7))) * 8];
      int brow = w * 16 + lm;
      short8 bfr = *(const short8*)&Bs[kh][(brow * 8 + ((ksl * 4 + q) ^ (brow & 7))) * 8];
      acc = __builtin_amdgcn_mfma_f32_16x16x32_bf16(af, bfr, acc, 0, 0, 0);
    }
    {
      int col = w * 16 + lm;
      float bc = bp2[nc * 128 + col];
#pragma unroll
      for (int r = 0; r < 4; ++r)
        pbuf[(q * 4 + r) * 132 + col] = siluf(acc[r] + bc);
    }
    __syncthreads();  // pbuf ready
    {
      float mv = (pbuf[(3 * ep + 0) * 132 + cc] + pbuf[(3 * ep + 1) * 132 + cc] +
                  pbuf[(3 * ep + 2) * 132 + cc]) * (1.f / 3.f);
      const float* wr = &wvp[ep][nc * 52];
#pragma unroll
      for (int b4 = 0; b4 < 12; ++b4) {
        float4 w4 = *(const float4*)&wr[b4 * 4];
        oacc[b4 * 4 + 0] += w4.x * mv;
        oacc[b4 * 4 + 1] += w4.y * mv;
        oacc[b4 * 4 + 2] += w4.z * mv;
        oacc[b4 * 4 + 3] += w4.w * mv;
      }
      oacc[48] += wr[48] * mv;
    }
  }
  const float s3 = 0.57735026918962576f;
#pragma unroll
  for (int b = 0; b < 49; ++b)
    out[(long)(e0 + ep) * 6272 + b * 128 + cc] = oacc[b] * s3;
}

// ---------------- host side ----------------
extern "C" void kernel_launch(void* const* d_in, const int* in_sizes, int n_in,
                              void* d_out, int out_size, void* d_ws, size_t ws_size,
                              hipStream_t stream) {
  (void)in_sizes; (void)n_in; (void)out_size; (void)ws_size;
  const float* x        = (const float*)d_in[0];
  const float* x_glovec = (const float*)d_in[2];
  const float* x_edge   = (const float*)d_in[3];
  const int*   eidx     = (const int*)d_in[4];
  const float* W_cg1   = (const float*)d_in[8];
  const float* W_cg21  = (const float*)d_in[9];
  const float* W_cg22  = (const float*)d_in[10];
  const float* Wn1a = (const float*)d_in[11];
  const float* bn1a = (const float*)d_in[12];
  const float* Wn1b = (const float*)d_in[13];
  const float* bn1b = (const float*)d_in[14];
  const float* Wn2a = (const float*)d_in[15];
  const float* bn2a = (const float*)d_in[16];
  const float* Wn2b = (const float*)d_in[17];
  const float* bn2b = (const float*)d_in[18];
  const float* Wd   = (const float*)d_in[19];
  const float* bd   = (const float*)d_in[20];
  const float* Wp1  = (const float*)d_in[21];
  const float* bp1  = (const float*)d_in[22];
  const float* Wp2  = (const float*)d_in[23];
  const float* bp2  = (const float*)d_in[24];
  const float* wigner     = (const float*)d_in[25];
  const float* wigner_inv = (const float*)d_in[26];
  const float* wig_node   = (const float*)d_in[27];

  char* W = (char*)d_ws;
  bf16*  featst = (bf16*)(W + 0);            // 8192 x 2112 bf16 (34.6 MB)
  float* p_osum = (float*)(W + 34603008);    // 4096 x 2048 f32 (33.5 MB)
  bf16*  msg    = (bf16*)(W + 135266304);    // 12288 x 2048 bf16 (50.3 MB)
  bf16*  hstack = (bf16*)(W + 185597952);    // 8192 x 128 bf16
  bf16*  m1     = (bf16*)(W + 187695104);    // 12288 x 128 bf16
  float* p_xe   = (float*)(W + 190840832);   // 4096 x 128 f32
  float* p_xmean= (float*)(W + 192937984);   // 100352 f32
  bf16*  BTa    = (bf16*)(W + 194142208);    // 2 x 128 x 2112
  bf16*  BTb    = (bf16*)(W + 195223552);    // 2 x 2048 x 128
  bf16*  BTp1   = (bf16*)(W + 196272128);    // 128 x 2048
  bf16*  BTp2   = (bf16*)(W + 196796416);    // 2048 x 128 (ends 197320704)
  float* p_asum = (float*)(W + 197320704);   // 4096 x 64 f32 (1 MB)
  float* p_mid  = (float*)(W + 198369280);   // 4096 x 32 f32 (512 KB)
  bf16*  BT1    = (bf16*)(W + 198893568);    // 32 x 2432 bf16 (152 KB)
  bf16*  BT2    = (bf16*)(W + 199049216);    // 64 x 2496 bf16 (312 KB; ends 199368704)

  TJobs tj;
  tj.j[0] = {Wn1a, BTa,            2064, 128, 2112};
  tj.j[1] = {Wn2a, BTa + 270336,   2064, 128, 2112};
  tj.j[2] = {Wn1b, BTb,            128, 2048, 128};
  tj.j[3] = {Wn2b, BTb + 262144,   128, 2048, 128};
  tj.j[4] = {Wp1,  BTp1,           2048, 128, 2048};
  tj.j[5] = {Wp2,  BTp2,           128, 2048, 128};
  transpose_cvt_kernel<<<dim3(1056, 6), 256, 0, stream>>>(tj);
  cg_prep_kernel<<<dim3(624, 2), 256, 0, stream>>>(W_cg1, W_cg21, W_cg22, BT1, BT2);

  node_mean_kernel<<<(NN * LL) / 4, 256, 0, stream>>>(x, p_xmean);
  // CG bilinears: A generated on the fly inside the GEMM (no P1/P2 materialization)
  cg1_kernel<<<EE / 32, 256, 0, stream>>>(p_xmean, eidx, BT1, p_mid);
  cg2_kernel<<<EE / 32, 256, 0, stream>>>(p_xmean, p_mid, eidx, BT2, p_asum);

  gemm_f32_silu<<<dim3(EE / 64, 2), 256, 0, stream>>>(x_edge, Wd, bd, p_xe, EE, HH, 128);
  build_feat_kernel<<<EE, 256, 0, stream>>>(x, x_glovec, wig_node, eidx, featst);
  // h = silu(feat @ Wna): M=8192, N=128, K=2112, stacked weights (BM=32 -> 256 blocks)
  gemm_mfma<32, true, false, true><<<dim3(256, 1), 256, 0, stream>>>(
      featst, BTa, BTa + 270336, bn1a, bn2a, nullptr, hstack, 8192, 128, 2112, 4096);
  // osum = silu(h1 @ Wn1b + b1) + silu(h2 @ Wn2b + b2): M=4096, N=2048, K=128
  gemm_osum<<<dim3(32, 16), 256, 0, stream>>>(hstack, BTb, BTb + 262144, bn1b, bn2b, p_osum);
  // fused rotback + z-build + msg GEMM
  rotate_msg_fused_kernel<<<EE, 512, 0, stream>>>(
      x, wigner, eidx, p_asum, p_osum, wig_node, msg);
  // m1 = silu(msg @ Wp1) * xe: M=12288, N=128, K=2048, bf16 out (BM=32 -> 384 blocks)
  gemm_mfma<32, true, true, true><<<dim3(384, 1), 256, 0, stream>>>(
      msg, BTp1, BTp1, bp1, bp1, p_xe, m1, 12288, 128, 2048, 1 << 30);
  // fused m2 GEMM + mean_ny + RotateInv -> out (register-accumulated)
  m2out_kernel<<<EE / 4, 512, 0, stream>>>(m1, BTp2, bp2, wigner_inv, (float*)d_out);
}

// Round 6
// 644.143 us; speedup vs baseline: 1.0192x; 1.0192x over previous
//
#include <hip/hip_runtime.h>
#include <hip/hip_bf16.h>

typedef __hip_bfloat16 bf16;
typedef __attribute__((ext_vector_type(8))) short short8;
typedef __attribute__((ext_vector_type(4))) float f32x4;

#define NN 2048
#define EE 4096
#define LL 49
#define LRR 16
#define NYY 3
#define CC 128
#define HH 128

#define K1P 2432   // 2401 padded to x64 (BT1 K)
#define K2P 2496   // 2450 padded to x64 (BT2 K)

__device__ __forceinline__ float siluf(float v) { return v * (1.0f / (1.0f + __expf(-v))); }
__device__ __forceinline__ bf16 f2b(float v) { return __float2bfloat16(v); }
__device__ __forceinline__ float getc(float4 v, int i) {
  return i == 0 ? v.x : i == 1 ? v.y : i == 2 ? v.z : v.w;
}

// ---------------- weight convert + transpose: out[n*Kp+k] = bf16(in[k*N+n]), zero-pad k>=K ----------------
struct TJob { const float* in; bf16* out; int K, N, Kp; };
struct TJobs { TJob j[6]; };

__global__ __launch_bounds__(256) void transpose_cvt_kernel(TJobs jobs) {
  TJob jb = jobs.j[blockIdx.y];
  int i = blockIdx.x * 256 + threadIdx.x;
  if (i < jb.N * jb.Kp) {
    int n = i / jb.Kp, k = i - n * jb.Kp;
    jb.out[i] = (k < jb.K) ? f2b(jb.in[(long)k * jb.N + n]) : f2b(0.f);
  }
}

// ---------------- CG weight prep: BT1[32][K1P], BT2[64][K2P] (transposed, bf16, zero-padded) ----------------
__global__ __launch_bounds__(256) void cg_prep_kernel(
    const float* __restrict__ Wcg1, const float* __restrict__ Wcg21,
    const float* __restrict__ Wcg22, bf16* __restrict__ BT1, bf16* __restrict__ BT2) {
  int i = blockIdx.x * 256 + threadIdx.x;
  if (blockIdx.y == 0) {
    if (i < 32 * K1P) {
      int o = i / K1P, k = i - o * K1P;
      float v = (o < 25 && k < 2401) ? Wcg1[k * 25 + o] : 0.f;
      BT1[i] = f2b(v);
    }
  } else {
    if (i < 64 * K2P) {
      int o = i / K2P, k = i - o * K2P;
      float v = 0.f;
      if (o < 49) {
        if (k < 1225) v = Wcg21[k * 49 + o];
        else if (k < 2450) v = Wcg22[(k - 1225) * 49 + o];
      }
      BT2[i] = f2b(v);
    }
  }
}

// ---------------- per-node channel mean ----------------
__global__ __launch_bounds__(256) void node_mean_kernel(const float* __restrict__ x,
                                                        float* __restrict__ xmean) {
  int row = blockIdx.x * 4 + (threadIdx.x >> 6);
  int lane = threadIdx.x & 63;
  const float* p = x + (long)row * CC;
  float s = p[lane] + p[lane + 64];
  for (int off = 32; off > 0; off >>= 1) s += __shfl_down(s, off);
  if (lane == 0) xmean[row] = s * (1.0f / 128.0f);
}

// ---------------- cg1: mid[e][o] = (xm_e (x) ym_e) @ BT1^T, A generated on the fly ----------------
// 32 edges/block, M=32, N=32, K=K1P. grid 128 x 256 threads.
__global__ __launch_bounds__(256) void cg1_kernel(
    const float* __restrict__ xmean, const int* __restrict__ eidx,
    const bf16* __restrict__ BT1, float* __restrict__ mid) {
  __shared__ float sxm[32 * 49], sym[32 * 49];
  __shared__ bf16 As[32 * 64];
  __shared__ bf16 Bs[32 * 64];
  __shared__ int se[32], de[32];
  const int tid = threadIdx.x, w = tid >> 6, lane = tid & 63;
  const int lm = lane & 15, q = lane >> 4;
  const int e0 = blockIdx.x * 32;
  if (tid < 32) { se[tid] = eidx[e0 + tid]; de[tid] = eidx[EE + e0 + tid]; }
  __syncthreads();
  for (int i = tid; i < 32 * 49; i += 256) {
    int m = i / 49, l = i - m * 49;
    sxm[i] = xmean[se[m] * 49 + l];
    sym[i] = xmean[de[m] * 49 + l];
  }
  const int mi = w >> 1, ni = w & 1;
  f32x4 acc = (f32x4){0.f, 0.f, 0.f, 0.f};
  for (int k0 = 0; k0 < K1P; k0 += 64) {
    __syncthreads();
    // generate A tile: As[m][kk] = xm[m][i]*ym[m][j], k=k0+kk=i*49+j
    for (int idx = tid; idx < 2048; idx += 256) {
      int m = idx >> 6, kk = idx & 63;
      int k = k0 + kk;
      float v = 0.f;
      if (k < 2401) { int i = k / 49, j = k - i * 49; v = sxm[m * 49 + i] * sym[m * 49 + j]; }
      int k8 = kk >> 3;
      As[(m * 8 + (k8 ^ (m & 7))) * 8 + (kk & 7)] = f2b(v);
    }
    {  // stage B tile (1 uint4/thread)
      int n = tid >> 3, k8 = tid & 7;
      uint4 v = *(const uint4*)((const char*)BT1 + ((long)n * K1P + k0 + k8 * 8) * 2);
      *(uint4*)&Bs[(n * 8 + (k8 ^ (n & 7))) * 8] = v;
    }
    __syncthreads();
#pragma unroll
    for (int ks = 0; ks < 2; ++ks) {
      int am = mi * 16 + lm, bn = ni * 16 + lm;
      short8 af = *(const short8*)&As[(am * 8 + ((ks * 4 + q) ^ (am & 7))) * 8];
      short8 bfr = *(const short8*)&Bs[(bn * 8 + ((ks * 4 + q) ^ (bn & 7))) * 8];
      acc = __builtin_amdgcn_mfma_f32_16x16x32_bf16(af, bfr, acc, 0, 0, 0);
    }
  }
#pragma unroll
  for (int r = 0; r < 4; ++r)
    mid[(long)(e0 + mi * 16 + q * 4 + r) * 32 + ni * 16 + lm] = acc[r];
}

// ---------------- cg2: asum[e][o] = [xm (x) mid | ym (x) mid] @ BT2^T, A on the fly ----------------
// 32 edges/block, M=32, N=64, K=K2P. grid 128 x 256 threads.
__global__ __launch_bounds__(256) void cg2_kernel(
    const float* __restrict__ xmean, const float* __restrict__ mid,
    const int* __restrict__ eidx, const bf16* __restrict__ BT2,
    float* __restrict__ asum) {
  __shared__ float sxm[32 * 49], sym[32 * 49], smid[32 * 25];
  __shared__ bf16 As[32 * 64];
  __shared__ bf16 Bs[64 * 64];
  __shared__ int se[32], de[32];
  const int tid = threadIdx.x, w = tid >> 6, lane = tid & 63;
  const int lm = lane & 15, q = lane >> 4;
  const int e0 = blockIdx.x * 32;
  if (tid < 32) { se[tid] = eidx[e0 + tid]; de[tid] = eidx[EE + e0 + tid]; }
  __syncthreads();
  for (int i = tid; i < 32 * 49; i += 256) {
    int m = i / 49, l = i - m * 49;
    sxm[i] = xmean[se[m] * 49 + l];
    sym[i] = xmean[de[m] * 49 + l];
  }
  for (int i = tid; i < 32 * 25; i += 256) {
    int m = i / 25, l = i - m * 25;
    smid[i] = mid[(long)(e0 + m) * 32 + l];
  }
  const int ni = w;
  f32x4 acc[2];
  acc[0] = (f32x4){0.f, 0.f, 0.f, 0.f};
  acc[1] = (f32x4){0.f, 0.f, 0.f, 0.f};
  for (int k0 = 0; k0 < K2P; k0 += 64) {
    __syncthreads();
    for (int idx = tid; idx < 2048; idx += 256) {
      int m = idx >> 6, kk = idx & 63;
      int k = k0 + kk;
      float v = 0.f;
      if (k < 1225) {
        int i = k / 25, mm = k - i * 25;
        v = sxm[m * 49 + i] * smid[m * 25 + mm];
      } else if (k < 2450) {
        int kk2 = k - 1225;
        int i = kk2 / 25, mm = kk2 - i * 25;
        v = sym[m * 49 + i] * smid[m * 25 + mm];
      }
      int k8 = kk >> 3;
      As[(m * 8 + (k8 ^ (m & 7))) * 8 + (kk & 7)] = f2b(v);
    }
#pragma unroll
    for (int it = 0; it < 2; ++it) {  // stage B: 64 rows x 64 k
      int lc = it * 256 + tid;
      int n = lc >> 3, k8 = lc & 7;
      uint4 v = *(const uint4*)((const char*)BT2 + ((long)n * K2P + k0 + k8 * 8) * 2);
      *(uint4*)&Bs[(n * 8 + (k8 ^ (n & 7))) * 8] = v;
    }
    __syncthreads();
#pragma unroll
    for (int ks = 0; ks < 2; ++ks) {
      int bn = ni * 16 + lm;
      short8 bfr = *(const short8*)&Bs[(bn * 8 + ((ks * 4 + q) ^ (bn & 7))) * 8];
#pragma unroll
      for (int mi = 0; mi < 2; ++mi) {
        int am = mi * 16 + lm;
        short8 af = *(const short8*)&As[(am * 8 + ((ks * 4 + q) ^ (am & 7))) * 8];
        acc[mi] = __builtin_amdgcn_mfma_f32_16x16x32_bf16(af, bfr, acc[mi], 0, 0, 0);
      }
    }
  }
#pragma unroll
  for (int mi = 0; mi < 2; ++mi)
#pragma unroll
    for (int r = 0; r < 4; ++r)
      asum[(long)(e0 + mi * 16 + q * 4 + r) * 64 + ni * 16 + lm] = acc[mi][r];
}

// ---------------- feat build -> bf16 [8192][2112] (rows e, 4096+e), pad cols 2064..2111 = 0 ----------------
__global__ __launch_bounds__(256) void build_feat_kernel(
    const float* __restrict__ x, const float* __restrict__ x_glovec,
    const float* __restrict__ wig_node, const int* __restrict__ eidx,
    bf16* __restrict__ featst) {
  __shared__ float wig[256];
  __shared__ float xa[2048], xb[2048], tmp[2048];
  int e = blockIdx.x, tid = threadIdx.x;
  int s = eidx[e], d = eidx[EE + e];
  wig[tid] = wig_node[e * 256 + tid];
  if (tid < 48) {
    featst[(long)e * 2112 + 2064 + tid] = f2b(0.f);
    featst[(long)(EE + e) * 2112 + 2064 + tid] = f2b(0.f);
  }
  for (int i4 = tid; i4 < 512; i4 += 256) {
    int l = i4 >> 5, c4 = i4 & 31;
    *(float4*)&xa[l * 128 + c4 * 4] = *(const float4*)&x[((long)s * LL + l) * CC + c4 * 4];
    *(float4*)&xb[l * 128 + c4 * 4] = *(const float4*)&x[((long)d * LL + l) * CC + c4 * 4];
  }
  __syncthreads();
  for (int idx = tid; idx < 2048; idx += 256) {
    int i = idx >> 7, c = idx & 127;
    float a = 0.f;
#pragma unroll
    for (int j = 0; j < 16; ++j) a += wig[j * 16 + i] * xa[j * 128 + c];
    tmp[idx] = a;
    featst[(long)e * 2112 + i * 129 + c] = f2b(a);
  }
  __syncthreads();
  {
    int row = tid >> 4, t = tid & 15;
    float m = 0.f;
#pragma unroll
    for (int k = 0; k < 8; ++k) m += tmp[row * 128 + t + k * 16];
    m += __shfl_down(m, 8, 16);
    m += __shfl_down(m, 4, 16);
    m += __shfl_down(m, 2, 16);
    m += __shfl_down(m, 1, 16);
    if (t == 0)
      featst[(long)e * 2112 + row * 129 + 128] =
          f2b(m * (1.0f / 128.0f) * x_glovec[(long)d * 16 + row]);
  }
  __syncthreads();
  for (int idx = tid; idx < 2048; idx += 256) {
    int i = idx >> 7, c = idx & 127;
    float a = 0.f;
#pragma unroll
    for (int j = 0; j < 16; ++j) a += wig[j * 16 + i] * xb[j * 128 + c];
    tmp[idx] = a;
    featst[(long)(EE + e) * 2112 + i * 129 + c] = f2b(a);
  }
  __syncthreads();
  {
    int row = tid >> 4, t = tid & 15;
    float m = 0.f;
#pragma unroll
    for (int k = 0; k < 8; ++k) m += tmp[row * 128 + t + k * 16];
    m += __shfl_down(m, 8, 16);
    m += __shfl_down(m, 4, 16);
    m += __shfl_down(m, 2, 16);
    m += __shfl_down(m, 1, 16);
    if (t == 0)
      featst[(long)(EE + e) * 2112 + row * 129 + 128] =
          f2b(m * (1.0f / 128.0f) * x_glovec[(long)s * 16 + row]);
  }
}

// ---------------- fp32 tiled GEMM (only for tiny xe GEMM) ----------------
__global__ __launch_bounds__(256) void gemm_f32_silu(
    const float* __restrict__ A, const float* __restrict__ B,
    const float* __restrict__ bias, float* __restrict__ C, int M, int N, int K) {
  __shared__ float As[16][68];
  __shared__ float Bs[16][64];
  const int tid = threadIdx.x;
  const int bm = blockIdx.x * 64, bn = blockIdx.y * 64;
  const int tx = tid & 15, ty = tid >> 4;
  const int ar = tid >> 2, ak = (tid & 3) * 4;
  const int br = tid >> 4, bc = (tid & 15) * 4;
  float acc[4][4] = {};
  const float* Ap = A + (long)(bm + ar) * K + ak;
  const float* Bp = B + (long)br * N + bn + bc;
  for (int k0 = 0; k0 < K; k0 += 16) {
    const float4 av = *(const float4*)(Ap + k0);
    const float4 bv = *(const float4*)(Bp + (long)k0 * N);
    __syncthreads();
    As[ak + 0][ar] = av.x; As[ak + 1][ar] = av.y;
    As[ak + 2][ar] = av.z; As[ak + 3][ar] = av.w;
    *(float4*)&Bs[br][bc] = bv;
    __syncthreads();
#pragma unroll
    for (int k = 0; k < 16; ++k) {
      const float4 a = *(const float4*)&As[k][ty * 4];
      const float4 b = *(const float4*)&Bs[k][tx * 4];
      acc[0][0] += a.x * b.x; acc[0][1] += a.x * b.y; acc[0][2] += a.x * b.z; acc[0][3] += a.x * b.w;
      acc[1][0] += a.y * b.x; acc[1][1] += a.y * b.y; acc[1][2] += a.y * b.z; acc[1][3] += a.y * b.w;
      acc[2][0] += a.z * b.x; acc[2][1] += a.z * b.y; acc[2][2] += a.z * b.z; acc[2][3] += a.z * b.w;
      acc[3][0] += a.w * b.x; acc[3][1] += a.w * b.y; acc[3][2] += a.w * b.z; acc[3][3] += a.w * b.w;
    }
  }
#pragma unroll
  for (int i = 0; i < 4; ++i) {
    int row = bm + ty * 4 + i;
#pragma unroll
    for (int j = 0; j < 4; ++j) {
      int col = bn + tx * 4 + j;
      C[(long)row * N + col] = siluf(acc[i][j] + bias[col]);
    }
  }
}

// ---------------- bf16 MFMA GEMM: C = epi(A[MxK]bf16 @ BT[NxK]bf16^T + bias) ----------------
template <int BM, bool SILU, bool XE, bool OUT_BF16>
__global__ __launch_bounds__(256) void gemm_mfma(
    const bf16* __restrict__ A, const bf16* __restrict__ B0, const bf16* __restrict__ B1,
    const float* __restrict__ bias0, const float* __restrict__ bias1,
    const float* __restrict__ xe, void* __restrict__ Cout,
    int M, int N, int K, int half) {
  constexpr int MI = (BM + 31) / 32;
  __shared__ short As[BM * 64];
  __shared__ short Bs[128 * 64];
  const int tid = threadIdx.x;
  const int w = tid >> 6, lane = tid & 63;
  const int lm = lane & 15, q = lane >> 4;
  const int bm = blockIdx.x * BM, bn = blockIdx.y * 128;
  const int wm = (w & 1) * (BM / 2), wn = (w >> 1) * 64;
  const bf16* Bp = (bm < half) ? B0 : B1;
  const float* bias = (bm < half) ? bias0 : bias1;

  f32x4 acc[MI][4];
#pragma unroll
  for (int mi = 0; mi < MI; ++mi)
#pragma unroll
    for (int ni = 0; ni < 4; ++ni) acc[mi][ni] = (f32x4){0.f, 0.f, 0.f, 0.f};

  for (int k0 = 0; k0 < K; k0 += 64) {
    __syncthreads();
#pragma unroll
    for (int it = 0; it < BM / 32; ++it) {
      int lc = it * 256 + tid;
      int m = lc >> 3, k8 = lc & 7;
      uint4 v = *(const uint4*)((const char*)A + ((long)(bm + m) * K + k0 + k8 * 8) * 2);
      *(uint4*)&As[(m * 8 + (k8 ^ (m & 7))) * 8] = v;
    }
#pragma unroll
    for (int it = 0; it < 4; ++it) {
      int lc = it * 256 + tid;
      int n = lc >> 3, k8 = lc & 7;
      uint4 v = *(const uint4*)((const char*)Bp + ((long)(bn + n) * K + k0 + k8 * 8) * 2);
      *(uint4*)&Bs[(n * 8 + (k8 ^ (n & 7))) * 8] = v;
    }
    __syncthreads();
#pragma unroll
    for (int ks = 0; ks < 2; ++ks) {
      short8 af[MI], bfr[4];
#pragma unroll
      for (int mi = 0; mi < MI; ++mi) {
        int row = wm + mi * 16 + lm;
        af[mi] = *(const short8*)&As[row * 64 + ((ks * 4 + q) ^ (lm & 7)) * 8];
      }
#pragma unroll
      for (int ni = 0; ni < 4; ++ni) {
        int row = wn + ni * 16 + lm;
        bfr[ni] = *(const short8*)&Bs[row * 64 + ((ks * 4 + q) ^ (lm & 7)) * 8];
      }
#pragma unroll
      for (int mi = 0; mi < MI; ++mi)
#pragma unroll
        for (int ni = 0; ni < 4; ++ni)
          acc[mi][ni] = __builtin_amdgcn_mfma_f32_16x16x32_bf16(af[mi], bfr[ni], acc[mi][ni], 0, 0, 0);
    }
  }
#pragma unroll
  for (int mi = 0; mi < MI; ++mi) {
#pragma unroll
    for (int ni = 0; ni < 4; ++ni) {
      int col = bn + wn + ni * 16 + lm;
      float bcol = bias[col];
#pragma unroll
      for (int r = 0; r < 4; ++r) {
        int row = bm + wm + mi * 16 + q * 4 + r;
        float v = acc[mi][ni][r] + bcol;
        if (SILU) v = siluf(v);
        if (XE) v *= xe[(row / 3) * HH + col];
        if (OUT_BF16) ((bf16*)Cout)[(long)row * N + col] = f2b(v);
        else ((float*)Cout)[(long)row * N + col] = v;
      }
    }
  }
}

// ---------------- osum = silu(h1 @ Wn1b + b1) + silu(h2 @ Wn2b + b2): M=4096, N=2048, K=128 ----------------
__global__ __launch_bounds__(256) void gemm_osum(
    const bf16* __restrict__ A, const bf16* __restrict__ B0w, const bf16* __restrict__ B1w,
    const float* __restrict__ bias0, const float* __restrict__ bias1,
    float* __restrict__ osum) {
  __shared__ short As[128 * 64];
  __shared__ short Bs[128 * 64];
  const int tid = threadIdx.x;
  const int w = tid >> 6, lane = tid & 63;
  const int lm = lane & 15, q = lane >> 4;
  const int bm = blockIdx.x * 128, bn = blockIdx.y * 128;
  const int wm = (w & 1) * 64, wn = (w >> 1) * 64;
  f32x4 ov[4][4];
  f32x4 acc[4][4];
#pragma unroll
  for (int mi = 0; mi < 4; ++mi)
#pragma unroll
    for (int ni = 0; ni < 4; ++ni) acc[mi][ni] = (f32x4){0.f, 0.f, 0.f, 0.f};

#pragma unroll 1
  for (int src = 0; src < 2; ++src) {
    const bf16* Ap = A + (long)src * 4096 * 128;
    const bf16* Bp = src ? B1w : B0w;
#pragma unroll 1
    for (int k0 = 0; k0 < 128; k0 += 64) {
      __syncthreads();
#pragma unroll
      for (int it = 0; it < 4; ++it) {
        int lc = it * 256 + tid;
        int m = lc >> 3, k8 = lc & 7;
        uint4 v = *(const uint4*)((const char*)Ap + ((long)(bm + m) * 128 + k0 + k8 * 8) * 2);
        *(uint4*)&As[(m * 8 + (k8 ^ (m & 7))) * 8] = v;
      }
#pragma unroll
      for (int it = 0; it < 4; ++it) {
        int lc = it * 256 + tid;
        int n = lc >> 3, k8 = lc & 7;
        uint4 v = *(const uint4*)((const char*)Bp + ((long)(bn + n) * 128 + k0 + k8 * 8) * 2);
        *(uint4*)&Bs[(n * 8 + (k8 ^ (n & 7))) * 8] = v;
      }
      __syncthreads();
#pragma unroll
      for (int ks = 0; ks < 2; ++ks) {
        short8 af[4], bfr[4];
#pragma unroll
        for (int mi = 0; mi < 4; ++mi)
          af[mi] = *(const short8*)&As[(wm + mi * 16 + lm) * 64 + ((ks * 4 + q) ^ (lm & 7)) * 8];
#pragma unroll
        for (int ni = 0; ni < 4; ++ni)
          bfr[ni] = *(const short8*)&Bs[(wn + ni * 16 + lm) * 64 + ((ks * 4 + q) ^ (lm & 7)) * 8];
#pragma unroll
        for (int mi = 0; mi < 4; ++mi)
#pragma unroll
          for (int ni = 0; ni < 4; ++ni)
            acc[mi][ni] = __builtin_amdgcn_mfma_f32_16x16x32_bf16(af[mi], bfr[ni], acc[mi][ni], 0, 0, 0);
      }
    }
    if (src == 0) {
#pragma unroll
      for (int mi = 0; mi < 4; ++mi)
#pragma unroll
        for (int ni = 0; ni < 4; ++ni) {
          int col = bn + wn + ni * 16 + lm;
          float bc = bias0[col];
#pragma unroll
          for (int r = 0; r < 4; ++r) ov[mi][ni][r] = siluf(acc[mi][ni][r] + bc);
#pragma unroll
          for (int r = 0; r < 4; ++r) acc[mi][ni][r] = 0.f;
        }
    }
  }
#pragma unroll
  for (int mi = 0; mi < 4; ++mi)
#pragma unroll
    for (int ni = 0; ni < 4; ++ni) {
      int col = bn + wn + ni * 16 + lm;
      float bc = bias1[col];
#pragma unroll
      for (int r = 0; r < 4; ++r) {
        int row = bm + wm + mi * 16 + q * 4 + r;
        osum[(long)row * 2048 + col] = ov[mi][ni][r] + siluf(acc[mi][ni][r] + bc);
      }
    }
}

// ---------------- fused: sh = wig_node @ osum; z = 2(xs+xt)+asum+pad(sh); msg = wigner @ z ------------
// 512 threads / edge. Split-bf16 (hi/lo, 3 products) keeps fp32-equivalent accuracy.
__global__ __launch_bounds__(512, 4) void rotate_msg_fused_kernel(
    const float* __restrict__ x, const float* __restrict__ wigner,
    const int* __restrict__ eidx, const float* __restrict__ asum,
    const float* __restrict__ osum, const float* __restrict__ wig_node,
    bf16* __restrict__ msg) {
  __shared__ bf16 Ah[48 * 64], Al[48 * 64];        // wigner hi/lo, XOR-swizzled rows (12 KB)
  __shared__ bf16 zTh[128 * 64], zTl[128 * 64];    // z^T hi/lo, GEMM-B layout (32 KB)
  __shared__ float z[49 * 132];                    // fp32 z (25.9 KB)
  __shared__ float osum_s[16 * 128];               // (8 KB)
  __shared__ float wig[256];
  __shared__ float as_s[49];
  const int e = blockIdx.x, tid = threadIdx.x;
  const int s = eidx[e], d = eidx[EE + e];
  const int w = tid >> 6, lane = tid & 63;
  const int lm = lane & 15, q = lane >> 4;

  // ---- P1: stage everything (independent vector loads) ----
  if (tid < 49) as_s[tid] = asum[e * 64 + tid];
  if (tid >= 64 && tid < 128) {
    int i = tid - 64;
    *(float4*)&wig[i * 4] = *(const float4*)&wig_node[(long)e * 256 + i * 4];
  }
  *(float4*)&osum_s[tid * 4] = *(const float4*)&osum[(long)e * 2048 + tid * 4];
  for (int i = tid; i < 48 * 15; i += 512) {  // A zero-pad k in [49,64)
    int m = i / 15, k = 49 + (i - m * 15);
    int off = m * 64 + (((k >> 3) ^ (m & 7)) << 3) + (k & 7);
    Ah[off] = f2b(0.f); Al[off] = f2b(0.f);
  }
  for (int i4 = tid; i4 < 588; i4 += 512) {   // wigner -> Ah/Al (float4 loads)
    float4 v4 = *(const float4*)&wigner[(long)e * 2352 + i4 * 4];
    int i = i4 * 4;
    int m = i / 49, k = i - m * 49;
    float vv[4] = {v4.x, v4.y, v4.z, v4.w};
#pragma unroll
    for (int j = 0; j < 4; ++j) {
      bf16 h = f2b(vv[j]);
      bf16 l = f2b(vv[j] - __bfloat162float(h));
      int off = m * 64 + (((k >> 3) ^ (m & 7)) << 3) + (k & 7);
      Ah[off] = h; Al[off] = l;
      if (++k == 49) { k = 0; ++m; }
    }
  }
  __syncthreads();

  // ---- P2: z build (float4 writes, conflict-free), sh fused inline for rows l<16 ----
  {
    const float* xs = x + (long)s * (LL * CC);
    const float* xt = x + (long)d * (LL * CC);
    for (int i4 = tid; i4 < 49 * 32; i4 += 512) {
      int l = i4 >> 5, c4 = i4 & 31;
      float4 a = *(const float4*)&xs[l * 128 + c4 * 4];
      float4 b = *(const float4*)&xt[l * 128 + c4 * 4];
      float ad = as_s[l];
      float4 v;
      v.x = 2.f * (a.x + b.x) + ad;
      v.y = 2.f * (a.y + b.y) + ad;
      v.z = 2.f * (a.z + b.z) + ad;
      v.w = 2.f * (a.w + b.w) + ad;
      if (l < 16) {
#pragma unroll
        for (int j = 0; j < 16; ++j) {
          float wv = wig[l * 16 + j];                       // broadcast
          float4 o = *(const float4*)&osum_s[j * 128 + c4 * 4];
          v.x += wv * o.x; v.y += wv * o.y; v.z += wv * o.z; v.w += wv * o.w;
        }
      }
      *(float4*)&z[l * 132 + c4 * 4] = v;
    }
  }
  __syncthreads();

  // ---- P3: transpose via 4x float4 reads (conflict-free granule map) + 8B packed writes (2-way) ----
  {
    const int b0 = (tid & 15) * 4;
    const int c0 = (tid >> 4) * 4;
    float4 rv[4];
#pragma unroll
    for (int j = 0; j < 4; ++j)
      rv[j] = (b0 + j < 49) ? *(const float4*)&z[(b0 + j) * 132 + c0]
                            : (float4){0.f, 0.f, 0.f, 0.f};
#pragma unroll
    for (int i = 0; i < 4; ++i) {
      int c = c0 + i;
      union { bf16 b[4]; unsigned long long u; } hu, lu;
#pragma unroll
      for (int j = 0; j < 4; ++j) {
        float v = getc(rv[j], i);
        bf16 h = f2b(v);
        hu.b[j] = h;
        lu.b[j] = f2b(v - __bfloat162float(h));
      }
      int off = c * 64 + (((b0 >> 3) ^ (c & 7)) << 3) + (b0 & 7);
      *(unsigned long long*)&zTh[off] = hu.u;
      *(unsigned long long*)&zTl[off] = lu.u;
    }
  }
  __syncthreads();

  // ---- P4: MFMA (wave w -> n-tile w, m-tiles = NY taps) + store ----
  short8 ah[3][2], alo[3][2], bh[2], bl[2];
#pragma unroll
  for (int mi = 0; mi < 3; ++mi)
#pragma unroll
    for (int ks = 0; ks < 2; ++ks) {
      int off = (mi * 16 + lm) * 64 + (((ks * 4 + q) ^ (lm & 7)) << 3);
      ah[mi][ks] = *(const short8*)&Ah[off];
      alo[mi][ks] = *(const short8*)&Al[off];
    }
#pragma unroll
  for (int ks = 0; ks < 2; ++ks) {
    int off = (w * 16 + lm) * 64 + (((ks * 4 + q) ^ (lm & 7)) << 3);
    bh[ks] = *(const short8*)&zTh[off];
    bl[ks] = *(const short8*)&zTl[off];
  }
  f32x4 acc[3];
#pragma unroll
  for (int mi = 0; mi < 3; ++mi) acc[mi] = (f32x4){0.f, 0.f, 0.f, 0.f};
#pragma unroll
  for (int mi = 0; mi < 3; ++mi)
#pragma unroll
    for (int ks = 0; ks < 2; ++ks) {
      acc[mi] = __builtin_amdgcn_mfma_f32_16x16x32_bf16(ah[mi][ks], bh[ks], acc[mi], 0, 0, 0);
      acc[mi] = __builtin_amdgcn_mfma_f32_16x16x32_bf16(ah[mi][ks], bl[ks], acc[mi], 0, 0, 0);
      acc[mi] = __builtin_amdgcn_mfma_f32_16x16x32_bf16(alo[mi][ks], bh[ks], acc[mi], 0, 0, 0);
    }
  {
    int c = w * 16 + lm;
#pragma unroll
    for (int mi = 0; mi < 3; ++mi) {
      long base = ((long)e * 3 + mi) * 2048 + c;
#pragma unroll
      for (int r = 0; r < 4; ++r)
        msg[base + (q * 4 + r) * 128] = f2b(acc[mi][r]);
    }
  }
}

// ---------------- fused m2 GEMM + CombineYRotations + RotateInv: 4 edges / block ----------------
// R3 structure (LDS mr + separate rotation phase; no big per-thread arrays -> no spill)
// + T14 register-prefetch of the next Bs chunk to hide L2 latency across the compute phases.
__global__ __launch_bounds__(512) void m2out_kernel(
    const bf16* __restrict__ m1, const bf16* __restrict__ BTp2,
    const float* __restrict__ bp2, const float* __restrict__ wigner_inv,
    float* __restrict__ out) {
  __shared__ __align__(16) char sm[4096 + 32768 + 8448 + 32768];
  short (*As)[1024] = (short(*)[1024])sm;                  // [2][16*64]
  short (*Bs)[8192] = (short(*)[8192])(sm + 4096);         // [2][128*64]
  float* pbuf = (float*)(sm + 4096 + 32768);               // [16*132]
  float* mr   = (float*)(sm + 4096 + 32768 + 8448);        // [4*2048]
  float* wv_s = (float*)(sm + 4096);                       // alias of Bs (used after chunk loop)

  const int tid = threadIdx.x;
  const int w = tid >> 6, lane = tid & 63;
  const int lm = lane & 15, q = lane >> 4;
  const int e0 = blockIdx.x * 4;

  // stage A: 12 real rows of m1 -> 16 padded, swizzled per 64-k half
  if (tid < 256) {
    int n = tid >> 4, k8 = tid & 15;
    uint4 v = (uint4){0, 0, 0, 0};
    if (n < 12) v = *(const uint4*)((const char*)m1 + ((long)(e0 * 3 + n) * 128 + k8 * 8) * 2);
    *(uint4*)&As[k8 >> 3][(n * 8 + ((k8 & 7) ^ (n & 7))) * 8] = v;
  }

  // prefetch B chunk 0 into regs
  uint4 bv[4];
#pragma unroll
  for (int it = 0; it < 4; ++it) {
    int lc = it * 512 + tid;
    int n = lc >> 4, k8 = lc & 15;
    bv[it] = *(const uint4*)((const char*)BTp2 + ((long)n * 128 + k8 * 8) * 2);
  }

#pragma unroll 1
  for (int nc = 0; nc < 16; ++nc) {
    // write Bs from regs, then issue next chunk's loads (hide L2 latency under compute)
#pragma unroll
    for (int it = 0; it < 4; ++it) {
      int lc = it * 512 + tid;
      int n = lc >> 4, k8 = lc & 15;
      *(uint4*)&Bs[k8 >> 3][(n * 8 + ((k8 & 7) ^ (n & 7))) * 8] = bv[it];
    }
    if (nc < 15) {
#pragma unroll
      for (int it = 0; it < 4; ++it) {
        int lc = it * 512 + tid;
        int n = lc >> 4, k8 = lc & 15;
        bv[it] = *(const uint4*)((const char*)BTp2 + ((long)((nc + 1) * 128 + n) * 128 + k8 * 8) * 2);
      }
    }
    __syncthreads();  // Bs ready (also As on first iter)
    f32x4 acc = (f32x4){0.f, 0.f, 0.f, 0.f};
#pragma unroll
    for (int ks = 0; ks < 4; ++ks) {
      int kh = ks >> 1, ksl = ks & 1;
      short8 af = *(const short8*)&As[kh][(lm * 8 + ((ksl * 4 + q) ^ (lm & 7))) * 8];
      int brow = w * 16 + lm;
      short8 bfr = *(const short8*)&Bs[kh][(brow * 8 + ((ksl * 4 + q) ^ (brow & 7))) * 8];
      acc = __builtin_amdgcn_mfma_f32_16x16x32_bf16(af, bfr, acc, 0, 0, 0);
    }
    {
      int col = w * 16 + lm;
      float bc = bp2[nc * 128 + col];
#pragma unroll
      for (int r = 0; r < 4; ++r)
        pbuf[(q * 4 + r) * 132 + col] = siluf(acc[r] + bc);
    }
    __syncthreads();  // pbuf ready
    {
      int c = tid & 127, e4 = tid >> 7;
      mr[e4 * 2048 + nc * 128 + c] =
          (pbuf[(3 * e4 + 0) * 132 + c] + pbuf[(3 * e4 + 1) * 132 + c] +
           pbuf[(3 * e4 + 2) * 132 + c]) * (1.f / 3.f);
    }
  }
  __syncthreads();
  // stage wigner_inv for 4 edges (3136 floats, aliases Bs)
  for (int i4 = tid; i4 < 784; i4 += 512)
    *(float4*)&wv_s[i4 * 4] = *(const float4*)&wigner_inv[(long)e0 * 784 + i4 * 4];
  __syncthreads();
  // rotation: out[e][b][c] = inv_sqrt3 * sum_r wv[e][b*16+r] * mr[e][r*128+c]
  {
    const int c4 = tid & 31, sb = (tid >> 5) & 3, ep = tid >> 7;
#pragma unroll 1
    for (int bb = 0; bb < 13; ++bb) {
      int b = bb * 4 + sb;
      if (b < 49) {
        float a0 = 0.f, a1 = 0.f, a2 = 0.f, a3 = 0.f;
#pragma unroll
        for (int r = 0; r < 16; ++r) {
          float wvv = wv_s[ep * 784 + b * 16 + r];
          const float4 m = *(const float4*)&mr[ep * 2048 + r * 128 + c4 * 4];
          a0 += wvv * m.x; a1 += wvv * m.y; a2 += wvv * m.z; a3 += wvv * m.w;
        }
        float4 o;
        o.x = a0 * 0.57735026918962576f; o.y = a1 * 0.57735026918962576f;
        o.z = a2 * 0.57735026918962576f; o.w = a3 * 0.57735026918962576f;
        *(float4*)&out[(long)(e0 + ep) * 6272 + b * 128 + c4 * 4] = o;
      }
    }
  }
}

// ---------------- host side ----------------
extern "C" void kernel_launch(void* const* d_in, const int* in_sizes, int n_in,
                              void* d_out, int out_size, void* d_ws, size_t ws_size,
                              hipStream_t stream) {
  (void)in_sizes; (void)n_in; (void)out_size; (void)ws_size;
  const float* x        = (const float*)d_in[0];
  const float* x_glovec = (const float*)d_in[2];
  const float* x_edge   = (const float*)d_in[3];
  const int*   eidx     = (const int*)d_in[4];
  const float* W_cg1   = (const float*)d_in[8];
  const float* W_cg21  = (const float*)d_in[9];
  const float* W_cg22  = (const float*)d_in[10];
  const float* Wn1a = (const float*)d_in[11];
  const float* bn1a = (const float*)d_in[12];
  const float* Wn1b = (const float*)d_in[13];
  const float* bn1b = (const float*)d_in[14];
  const float* Wn2a = (const float*)d_in[15];
  const float* bn2a = (const float*)d_in[16];
  const float* Wn2b = (const float*)d_in[17];
  const float* bn2b = (const float*)d_in[18];
  const float* Wd   = (const float*)d_in[19];
  const float* bd   = (const float*)d_in[20];
  const float* Wp1  = (const float*)d_in[21];
  const float* bp1  = (const float*)d_in[22];
  const float* Wp2  = (const float*)d_in[23];
  const float* bp2  = (const float*)d_in[24];
  const float* wigner     = (const float*)d_in[25];
  const float* wigner_inv = (const float*)d_in[26];
  const float* wig_node   = (const float*)d_in[27];

  char* W = (char*)d_ws;
  bf16*  featst = (bf16*)(W + 0);            // 8192 x 2112 bf16 (34.6 MB)
  float* p_osum = (float*)(W + 34603008);    // 4096 x 2048 f32 (33.5 MB)
  bf16*  msg    = (bf16*)(W + 135266304);    // 12288 x 2048 bf16 (50.3 MB)
  bf16*  hstack = (bf16*)(W + 185597952);    // 8192 x 128 bf16
  bf16*  m1     = (bf16*)(W + 187695104);    // 12288 x 128 bf16
  float* p_xe   = (float*)(W + 190840832);   // 4096 x 128 f32
  float* p_xmean= (float*)(W + 192937984);   // 100352 f32
  bf16*  BTa    = (bf16*)(W + 194142208);    // 2 x 128 x 2112
  bf16*  BTb    = (bf16*)(W + 195223552);    // 2 x 2048 x 128
  bf16*  BTp1   = (bf16*)(W + 196272128);    // 128 x 2048
  bf16*  BTp2   = (bf16*)(W + 196796416);    // 2048 x 128 (ends 197320704)
  float* p_asum = (float*)(W + 197320704);   // 4096 x 64 f32 (1 MB)
  float* p_mid  = (float*)(W + 198369280);   // 4096 x 32 f32 (512 KB)
  bf16*  BT1    = (bf16*)(W + 198893568);    // 32 x 2432 bf16 (152 KB)
  bf16*  BT2    = (bf16*)(W + 199049216);    // 64 x 2496 bf16 (312 KB; ends 199368704)

  TJobs tj;
  tj.j[0] = {Wn1a, BTa,            2064, 128, 2112};
  tj.j[1] = {Wn2a, BTa + 270336,   2064, 128, 2112};
  tj.j[2] = {Wn1b, BTb,            128, 2048, 128};
  tj.j[3] = {Wn2b, BTb + 262144,   128, 2048, 128};
  tj.j[4] = {Wp1,  BTp1,           2048, 128, 2048};
  tj.j[5] = {Wp2,  BTp2,           128, 2048, 128};
  transpose_cvt_kernel<<<dim3(1056, 6), 256, 0, stream>>>(tj);
  cg_prep_kernel<<<dim3(624, 2), 256, 0, stream>>>(W_cg1, W_cg21, W_cg22, BT1, BT2);

  node_mean_kernel<<<(NN * LL) / 4, 256, 0, stream>>>(x, p_xmean);
  // CG bilinears: A generated on the fly inside the GEMM (no P1/P2 materialization)
  cg1_kernel<<<EE / 32, 256, 0, stream>>>(p_xmean, eidx, BT1, p_mid);
  cg2_kernel<<<EE / 32, 256, 0, stream>>>(p_xmean, p_mid, eidx, BT2, p_asum);

  gemm_f32_silu<<<dim3(EE / 64, 2), 256, 0, stream>>>(x_edge, Wd, bd, p_xe, EE, HH, 128);
  build_feat_kernel<<<EE, 256, 0, stream>>>(x, x_glovec, wig_node, eidx, featst);
  // h = silu(feat @ Wna): M=8192, N=128, K=2112, stacked weights (BM=32 -> 256 blocks)
  gemm_mfma<32, true, false, true><<<dim3(256, 1), 256, 0, stream>>>(
      featst, BTa, BTa + 270336, bn1a, bn2a, nullptr, hstack, 8192, 128, 2112, 4096);
  // osum = silu(h1 @ Wn1b + b1) + silu(h2 @ Wn2b + b2): M=4096, N=2048, K=128
  gemm_osum<<<dim3(32, 16), 256, 0, stream>>>(hstack, BTb, BTb + 262144, bn1b, bn2b, p_osum);
  // fused rotback + z-build + msg GEMM
  rotate_msg_fused_kernel<<<EE, 512, 0, stream>>>(
      x, wigner, eidx, p_asum, p_osum, wig_node, msg);
  // m1 = silu(msg @ Wp1) * xe: M=12288, N=128, K=2048, bf16 out (BM=32 -> 384 blocks)
  gemm_mfma<32, true, true, true><<<dim3(384, 1), 256, 0, stream>>>(
      msg, BTp1, BTp1, bp1, bp1, p_xe, m1, 12288, 128, 2048, 1 << 30);
  // fused m2 GEMM + mean_ny + RotateInv -> out (R3 structure + Bs reg-prefetch)
  m2out_kernel<<<EE / 4, 512, 0, stream>>>(m1, BTp2, bp2, wigner_inv, (float*)d_out);
}

// Round 7
// 544.841 us; speedup vs baseline: 1.2050x; 1.1823x over previous
//
#include <hip/hip_runtime.h>
#include <hip/hip_bf16.h>

typedef __hip_bfloat16 bf16;
typedef __attribute__((ext_vector_type(8))) short short8;
typedef __attribute__((ext_vector_type(4))) float f32x4;

#define NN 2048
#define EE 4096
#define LL 49
#define LRR 16
#define NYY 3
#define CC 128
#define HH 128

#define K1P 2432   // 2401 padded to x64 (BT1 K)
#define K2P 2496   // 2450 padded to x64 (BT2 K)

__device__ __forceinline__ float siluf(float v) { return v * (1.0f / (1.0f + __expf(-v))); }
__device__ __forceinline__ bf16 f2b(float v) { return __float2bfloat16(v); }
__device__ __forceinline__ float getc(float4 v, int i) {
  return i == 0 ? v.x : i == 1 ? v.y : i == 2 ? v.z : v.w;
}

// ---------------- weight convert + transpose: out[n*Kp+k] = bf16(in[k*N+n]), zero-pad k>=K ----------------
struct TJob { const float* in; bf16* out; int K, N, Kp; };
struct TJobs { TJob j[6]; };

__global__ __launch_bounds__(256) void transpose_cvt_kernel(TJobs jobs) {
  TJob jb = jobs.j[blockIdx.y];
  int i = blockIdx.x * 256 + threadIdx.x;
  if (i < jb.N * jb.Kp) {
    int n = i / jb.Kp, k = i - n * jb.Kp;
    jb.out[i] = (k < jb.K) ? f2b(jb.in[(long)k * jb.N + n]) : f2b(0.f);
  }
}

// ---------------- CG weight prep: BT1[32][K1P], BT2[64][K2P] (transposed, bf16, zero-padded) ----------------
__global__ __launch_bounds__(256) void cg_prep_kernel(
    const float* __restrict__ Wcg1, const float* __restrict__ Wcg21,
    const float* __restrict__ Wcg22, bf16* __restrict__ BT1, bf16* __restrict__ BT2) {
  int i = blockIdx.x * 256 + threadIdx.x;
  if (blockIdx.y == 0) {
    if (i < 32 * K1P) {
      int o = i / K1P, k = i - o * K1P;
      float v = (o < 25 && k < 2401) ? Wcg1[k * 25 + o] : 0.f;
      BT1[i] = f2b(v);
    }
  } else {
    if (i < 64 * K2P) {
      int o = i / K2P, k = i - o * K2P;
      float v = 0.f;
      if (o < 49) {
        if (k < 1225) v = Wcg21[k * 49 + o];
        else if (k < 2450) v = Wcg22[(k - 1225) * 49 + o];
      }
      BT2[i] = f2b(v);
    }
  }
}

// ---------------- per-node channel mean ----------------
__global__ __launch_bounds__(256) void node_mean_kernel(const float* __restrict__ x,
                                                        float* __restrict__ xmean) {
  int row = blockIdx.x * 4 + (threadIdx.x >> 6);
  int lane = threadIdx.x & 63;
  const float* p = x + (long)row * CC;
  float s = p[lane] + p[lane + 64];
  for (int off = 32; off > 0; off >>= 1) s += __shfl_down(s, off);
  if (lane == 0) xmean[row] = s * (1.0f / 128.0f);
}

// ---------------- cg1: mid[e][o] = (xm_e (x) ym_e) @ BT1^T, A generated on the fly ----------------
// 32 edges/block, M=32, N=32, K=K1P. grid 128 x 256 threads.
__global__ __launch_bounds__(256) void cg1_kernel(
    const float* __restrict__ xmean, const int* __restrict__ eidx,
    const bf16* __restrict__ BT1, float* __restrict__ mid) {
  __shared__ float sxm[32 * 49], sym[32 * 49];
  __shared__ bf16 As[32 * 64];
  __shared__ bf16 Bs[32 * 64];
  __shared__ int se[32], de[32];
  const int tid = threadIdx.x, w = tid >> 6, lane = tid & 63;
  const int lm = lane & 15, q = lane >> 4;
  const int e0 = blockIdx.x * 32;
  if (tid < 32) { se[tid] = eidx[e0 + tid]; de[tid] = eidx[EE + e0 + tid]; }
  __syncthreads();
  for (int i = tid; i < 32 * 49; i += 256) {
    int m = i / 49, l = i - m * 49;
    sxm[i] = xmean[se[m] * 49 + l];
    sym[i] = xmean[de[m] * 49 + l];
  }
  const int mi = w >> 1, ni = w & 1;
  f32x4 acc = (f32x4){0.f, 0.f, 0.f, 0.f};
  for (int k0 = 0; k0 < K1P; k0 += 64) {
    __syncthreads();
    // generate A tile: As[m][kk] = xm[m][i]*ym[m][j], k=k0+kk=i*49+j
    for (int idx = tid; idx < 2048; idx += 256) {
      int m = idx >> 6, kk = idx & 63;
      int k = k0 + kk;
      float v = 0.f;
      if (k < 2401) { int i = k / 49, j = k - i * 49; v = sxm[m * 49 + i] * sym[m * 49 + j]; }
      int k8 = kk >> 3;
      As[(m * 8 + (k8 ^ (m & 7))) * 8 + (kk & 7)] = f2b(v);
    }
    {  // stage B tile (1 uint4/thread)
      int n = tid >> 3, k8 = tid & 7;
      uint4 v = *(const uint4*)((const char*)BT1 + ((long)n * K1P + k0 + k8 * 8) * 2);
      *(uint4*)&Bs[(n * 8 + (k8 ^ (n & 7))) * 8] = v;
    }
    __syncthreads();
#pragma unroll
    for (int ks = 0; ks < 2; ++ks) {
      int am = mi * 16 + lm, bn = ni * 16 + lm;
      short8 af = *(const short8*)&As[(am * 8 + ((ks * 4 + q) ^ (am & 7))) * 8];
      short8 bfr = *(const short8*)&Bs[(bn * 8 + ((ks * 4 + q) ^ (bn & 7))) * 8];
      acc = __builtin_amdgcn_mfma_f32_16x16x32_bf16(af, bfr, acc, 0, 0, 0);
    }
  }
#pragma unroll
  for (int r = 0; r < 4; ++r)
    mid[(long)(e0 + mi * 16 + q * 4 + r) * 32 + ni * 16 + lm] = acc[r];
}

// ---------------- cg2: asum[e][o] = [xm (x) mid | ym (x) mid] @ BT2^T, A on the fly ----------------
// 32 edges/block, M=32, N=64, K=K2P. grid 128 x 256 threads.
__global__ __launch_bounds__(256) void cg2_kernel(
    const float* __restrict__ xmean, const float* __restrict__ mid,
    const int* __restrict__ eidx, const bf16* __restrict__ BT2,
    float* __restrict__ asum) {
  __shared__ float sxm[32 * 49], sym[32 * 49], smid[32 * 25];
  __shared__ bf16 As[32 * 64];
  __shared__ bf16 Bs[64 * 64];
  __shared__ int se[32], de[32];
  const int tid = threadIdx.x, w = tid >> 6, lane = tid & 63;
  const int lm = lane & 15, q = lane >> 4;
  const int e0 = blockIdx.x * 32;
  if (tid < 32) { se[tid] = eidx[e0 + tid]; de[tid] = eidx[EE + e0 + tid]; }
  __syncthreads();
  for (int i = tid; i < 32 * 49; i += 256) {
    int m = i / 49, l = i - m * 49;
    sxm[i] = xmean[se[m] * 49 + l];
    sym[i] = xmean[de[m] * 49 + l];
  }
  for (int i = tid; i < 32 * 25; i += 256) {
    int m = i / 25, l = i - m * 25;
    smid[i] = mid[(long)(e0 + m) * 32 + l];
  }
  const int ni = w;
  f32x4 acc[2];
  acc[0] = (f32x4){0.f, 0.f, 0.f, 0.f};
  acc[1] = (f32x4){0.f, 0.f, 0.f, 0.f};
  for (int k0 = 0; k0 < K2P; k0 += 64) {
    __syncthreads();
    for (int idx = tid; idx < 2048; idx += 256) {
      int m = idx >> 6, kk = idx & 63;
      int k = k0 + kk;
      float v = 0.f;
      if (k < 1225) {
        int i = k / 25, mm = k - i * 25;
        v = sxm[m * 49 + i] * smid[m * 25 + mm];
      } else if (k < 2450) {
        int kk2 = k - 1225;
        int i = kk2 / 25, mm = kk2 - i * 25;
        v = sym[m * 49 + i] * smid[m * 25 + mm];
      }
      int k8 = kk >> 3;
      As[(m * 8 + (k8 ^ (m & 7))) * 8 + (kk & 7)] = f2b(v);
    }
#pragma unroll
    for (int it = 0; it < 2; ++it) {  // stage B: 64 rows x 64 k
      int lc = it * 256 + tid;
      int n = lc >> 3, k8 = lc & 7;
      uint4 v = *(const uint4*)((const char*)BT2 + ((long)n * K2P + k0 + k8 * 8) * 2);
      *(uint4*)&Bs[(n * 8 + (k8 ^ (n & 7))) * 8] = v;
    }
    __syncthreads();
#pragma unroll
    for (int ks = 0; ks < 2; ++ks) {
      int bn = ni * 16 + lm;
      short8 bfr = *(const short8*)&Bs[(bn * 8 + ((ks * 4 + q) ^ (bn & 7))) * 8];
#pragma unroll
      for (int mi = 0; mi < 2; ++mi) {
        int am = mi * 16 + lm;
        short8 af = *(const short8*)&As[(am * 8 + ((ks * 4 + q) ^ (am & 7))) * 8];
        acc[mi] = __builtin_amdgcn_mfma_f32_16x16x32_bf16(af, bfr, acc[mi], 0, 0, 0);
      }
    }
  }
#pragma unroll
  for (int mi = 0; mi < 2; ++mi)
#pragma unroll
    for (int r = 0; r < 4; ++r)
      asum[(long)(e0 + mi * 16 + q * 4 + r) * 64 + ni * 16 + lm] = acc[mi][r];
}

// ---------------- feat build -> bf16 [8192][2112] (rows e, 4096+e), pad cols 2064..2111 = 0 ----------------
__global__ __launch_bounds__(256) void build_feat_kernel(
    const float* __restrict__ x, const float* __restrict__ x_glovec,
    const float* __restrict__ wig_node, const int* __restrict__ eidx,
    bf16* __restrict__ featst) {
  __shared__ float wig[256];
  __shared__ float xa[2048], xb[2048], tmp[2048];
  int e = blockIdx.x, tid = threadIdx.x;
  int s = eidx[e], d = eidx[EE + e];
  wig[tid] = wig_node[e * 256 + tid];
  if (tid < 48) {
    featst[(long)e * 2112 + 2064 + tid] = f2b(0.f);
    featst[(long)(EE + e) * 2112 + 2064 + tid] = f2b(0.f);
  }
  for (int i4 = tid; i4 < 512; i4 += 256) {
    int l = i4 >> 5, c4 = i4 & 31;
    *(float4*)&xa[l * 128 + c4 * 4] = *(const float4*)&x[((long)s * LL + l) * CC + c4 * 4];
    *(float4*)&xb[l * 128 + c4 * 4] = *(const float4*)&x[((long)d * LL + l) * CC + c4 * 4];
  }
  __syncthreads();
  for (int idx = tid; idx < 2048; idx += 256) {
    int i = idx >> 7, c = idx & 127;
    float a = 0.f;
#pragma unroll
    for (int j = 0; j < 16; ++j) a += wig[j * 16 + i] * xa[j * 128 + c];
    tmp[idx] = a;
    featst[(long)e * 2112 + i * 129 + c] = f2b(a);
  }
  __syncthreads();
  {
    int row = tid >> 4, t = tid & 15;
    float m = 0.f;
#pragma unroll
    for (int k = 0; k < 8; ++k) m += tmp[row * 128 + t + k * 16];
    m += __shfl_down(m, 8, 16);
    m += __shfl_down(m, 4, 16);
    m += __shfl_down(m, 2, 16);
    m += __shfl_down(m, 1, 16);
    if (t == 0)
      featst[(long)e * 2112 + row * 129 + 128] =
          f2b(m * (1.0f / 128.0f) * x_glovec[(long)d * 16 + row]);
  }
  __syncthreads();
  for (int idx = tid; idx < 2048; idx += 256) {
    int i = idx >> 7, c = idx & 127;
    float a = 0.f;
#pragma unroll
    for (int j = 0; j < 16; ++j) a += wig[j * 16 + i] * xb[j * 128 + c];
    tmp[idx] = a;
    featst[(long)(EE + e) * 2112 + i * 129 + c] = f2b(a);
  }
  __syncthreads();
  {
    int row = tid >> 4, t = tid & 15;
    float m = 0.f;
#pragma unroll
    for (int k = 0; k < 8; ++k) m += tmp[row * 128 + t + k * 16];
    m += __shfl_down(m, 8, 16);
    m += __shfl_down(m, 4, 16);
    m += __shfl_down(m, 2, 16);
    m += __shfl_down(m, 1, 16);
    if (t == 0)
      featst[(long)(EE + e) * 2112 + row * 129 + 128] =
          f2b(m * (1.0f / 128.0f) * x_glovec[(long)s * 16 + row]);
  }
}

// ---------------- fp32 tiled GEMM (only for tiny xe GEMM) ----------------
__global__ __launch_bounds__(256) void gemm_f32_silu(
    const float* __restrict__ A, const float* __restrict__ B,
    const float* __restrict__ bias, float* __restrict__ C, int M, int N, int K) {
  __shared__ float As[16][68];
  __shared__ float Bs[16][64];
  const int tid = threadIdx.x;
  const int bm = blockIdx.x * 64, bn = blockIdx.y * 64;
  const int tx = tid & 15, ty = tid >> 4;
  const int ar = tid >> 2, ak = (tid & 3) * 4;
  const int br = tid >> 4, bc = (tid & 15) * 4;
  float acc[4][4] = {};
  const float* Ap = A + (long)(bm + ar) * K + ak;
  const float* Bp = B + (long)br * N + bn + bc;
  for (int k0 = 0; k0 < K; k0 += 16) {
    const float4 av = *(const float4*)(Ap + k0);
    const float4 bv = *(const float4*)(Bp + (long)k0 * N);
    __syncthreads();
    As[ak + 0][ar] = av.x; As[ak + 1][ar] = av.y;
    As[ak + 2][ar] = av.z; As[ak + 3][ar] = av.w;
    *(float4*)&Bs[br][bc] = bv;
    __syncthreads();
#pragma unroll
    for (int k = 0; k < 16; ++k) {
      const float4 a = *(const float4*)&As[k][ty * 4];
      const float4 b = *(const float4*)&Bs[k][tx * 4];
      acc[0][0] += a.x * b.x; acc[0][1] += a.x * b.y; acc[0][2] += a.x * b.z; acc[0][3] += a.x * b.w;
      acc[1][0] += a.y * b.x; acc[1][1] += a.y * b.y; acc[1][2] += a.y * b.z; acc[1][3] += a.y * b.w;
      acc[2][0] += a.z * b.x; acc[2][1] += a.z * b.y; acc[2][2] += a.z * b.z; acc[2][3] += a.z * b.w;
      acc[3][0] += a.w * b.x; acc[3][1] += a.w * b.y; acc[3][2] += a.w * b.z; acc[3][3] += a.w * b.w;
    }
  }
#pragma unroll
  for (int i = 0; i < 4; ++i) {
    int row = bm + ty * 4 + i;
#pragma unroll
    for (int j = 0; j < 4; ++j) {
      int col = bn + tx * 4 + j;
      C[(long)row * N + col] = siluf(acc[i][j] + bias[col]);
    }
  }
}

// ---------------- bf16 MFMA GEMM: C = epi(A[MxK]bf16 @ BT[NxK]bf16^T + bias) ----------------
template <int BM, bool SILU, bool XE, bool OUT_BF16>
__global__ __launch_bounds__(256) void gemm_mfma(
    const bf16* __restrict__ A, const bf16* __restrict__ B0, const bf16* __restrict__ B1,
    const float* __restrict__ bias0, const float* __restrict__ bias1,
    const float* __restrict__ xe, void* __restrict__ Cout,
    int M, int N, int K, int half) {
  constexpr int MI = (BM + 31) / 32;
  __shared__ short As[BM * 64];
  __shared__ short Bs[128 * 64];
  const int tid = threadIdx.x;
  const int w = tid >> 6, lane = tid & 63;
  const int lm = lane & 15, q = lane >> 4;
  const int bm = blockIdx.x * BM, bn = blockIdx.y * 128;
  const int wm = (w & 1) * (BM / 2), wn = (w >> 1) * 64;
  const bf16* Bp = (bm < half) ? B0 : B1;
  const float* bias = (bm < half) ? bias0 : bias1;

  f32x4 acc[MI][4];
#pragma unroll
  for (int mi = 0; mi < MI; ++mi)
#pragma unroll
    for (int ni = 0; ni < 4; ++ni) acc[mi][ni] = (f32x4){0.f, 0.f, 0.f, 0.f};

  for (int k0 = 0; k0 < K; k0 += 64) {
    __syncthreads();
#pragma unroll
    for (int it = 0; it < BM / 32; ++it) {
      int lc = it * 256 + tid;
      int m = lc >> 3, k8 = lc & 7;
      uint4 v = *(const uint4*)((const char*)A + ((long)(bm + m) * K + k0 + k8 * 8) * 2);
      *(uint4*)&As[(m * 8 + (k8 ^ (m & 7))) * 8] = v;
    }
#pragma unroll
    for (int it = 0; it < 4; ++it) {
      int lc = it * 256 + tid;
      int n = lc >> 3, k8 = lc & 7;
      uint4 v = *(const uint4*)((const char*)Bp + ((long)(bn + n) * K + k0 + k8 * 8) * 2);
      *(uint4*)&Bs[(n * 8 + (k8 ^ (n & 7))) * 8] = v;
    }
    __syncthreads();
#pragma unroll
    for (int ks = 0; ks < 2; ++ks) {
      short8 af[MI], bfr[4];
#pragma unroll
      for (int mi = 0; mi < MI; ++mi) {
        int row = wm + mi * 16 + lm;
        af[mi] = *(const short8*)&As[row * 64 + ((ks * 4 + q) ^ (lm & 7)) * 8];
      }
#pragma unroll
      for (int ni = 0; ni < 4; ++ni) {
        int row = wn + ni * 16 + lm;
        bfr[ni] = *(const short8*)&Bs[row * 64 + ((ks * 4 + q) ^ (lm & 7)) * 8];
      }
#pragma unroll
      for (int mi = 0; mi < MI; ++mi)
#pragma unroll
        for (int ni = 0; ni < 4; ++ni)
          acc[mi][ni] = __builtin_amdgcn_mfma_f32_16x16x32_bf16(af[mi], bfr[ni], acc[mi][ni], 0, 0, 0);
    }
  }
#pragma unroll
  for (int mi = 0; mi < MI; ++mi) {
#pragma unroll
    for (int ni = 0; ni < 4; ++ni) {
      int col = bn + wn + ni * 16 + lm;
      float bcol = bias[col];
#pragma unroll
      for (int r = 0; r < 4; ++r) {
        int row = bm + wm + mi * 16 + q * 4 + r;
        float v = acc[mi][ni][r] + bcol;
        if (SILU) v = siluf(v);
        if (XE) v *= xe[(row / 3) * HH + col];
        if (OUT_BF16) ((bf16*)Cout)[(long)row * N + col] = f2b(v);
        else ((float*)Cout)[(long)row * N + col] = v;
      }
    }
  }
}

// ---------------- osum = silu(h1 @ Wn1b + b1) + silu(h2 @ Wn2b + b2): M=4096, N=2048, K=128 ----------------
__global__ __launch_bounds__(256) void gemm_osum(
    const bf16* __restrict__ A, const bf16* __restrict__ B0w, const bf16* __restrict__ B1w,
    const float* __restrict__ bias0, const float* __restrict__ bias1,
    float* __restrict__ osum) {
  __shared__ short As[128 * 64];
  __shared__ short Bs[128 * 64];
  const int tid = threadIdx.x;
  const int w = tid >> 6, lane = tid & 63;
  const int lm = lane & 15, q = lane >> 4;
  const int bm = blockIdx.x * 128, bn = blockIdx.y * 128;
  const int wm = (w & 1) * 64, wn = (w >> 1) * 64;
  f32x4 ov[4][4];
  f32x4 acc[4][4];
#pragma unroll
  for (int mi = 0; mi < 4; ++mi)
#pragma unroll
    for (int ni = 0; ni < 4; ++ni) acc[mi][ni] = (f32x4){0.f, 0.f, 0.f, 0.f};

#pragma unroll 1
  for (int src = 0; src < 2; ++src) {
    const bf16* Ap = A + (long)src * 4096 * 128;
    const bf16* Bp = src ? B1w : B0w;
#pragma unroll 1
    for (int k0 = 0; k0 < 128; k0 += 64) {
      __syncthreads();
#pragma unroll
      for (int it = 0; it < 4; ++it) {
        int lc = it * 256 + tid;
        int m = lc >> 3, k8 = lc & 7;
        uint4 v = *(const uint4*)((const char*)Ap + ((long)(bm + m) * 128 + k0 + k8 * 8) * 2);
        *(uint4*)&As[(m * 8 + (k8 ^ (m & 7))) * 8] = v;
      }
#pragma unroll
      for (int it = 0; it < 4; ++it) {
        int lc = it * 256 + tid;
        int n = lc >> 3, k8 = lc & 7;
        uint4 v = *(const uint4*)((const char*)Bp + ((long)(bn + n) * 128 + k0 + k8 * 8) * 2);
        *(uint4*)&Bs[(n * 8 + (k8 ^ (n & 7))) * 8] = v;
      }
      __syncthreads();
#pragma unroll
      for (int ks = 0; ks < 2; ++ks) {
        short8 af[4], bfr[4];
#pragma unroll
        for (int mi = 0; mi < 4; ++mi)
          af[mi] = *(const short8*)&As[(wm + mi * 16 + lm) * 64 + ((ks * 4 + q) ^ (lm & 7)) * 8];
#pragma unroll
        for (int ni = 0; ni < 4; ++ni)
          bfr[ni] = *(const short8*)&Bs[(wn + ni * 16 + lm) * 64 + ((ks * 4 + q) ^ (lm & 7)) * 8];
#pragma unroll
        for (int mi = 0; mi < 4; ++mi)
#pragma unroll
          for (int ni = 0; ni < 4; ++ni)
            acc[mi][ni] = __builtin_amdgcn_mfma_f32_16x16x32_bf16(af[mi], bfr[ni], acc[mi][ni], 0, 0, 0);
      }
    }
    if (src == 0) {
#pragma unroll
      for (int mi = 0; mi < 4; ++mi)
#pragma unroll
        for (int ni = 0; ni < 4; ++ni) {
          int col = bn + wn + ni * 16 + lm;
          float bc = bias0[col];
#pragma unroll
          for (int r = 0; r < 4; ++r) ov[mi][ni][r] = siluf(acc[mi][ni][r] + bc);
#pragma unroll
          for (int r = 0; r < 4; ++r) acc[mi][ni][r] = 0.f;
        }
    }
  }
#pragma unroll
  for (int mi = 0; mi < 4; ++mi)
#pragma unroll
    for (int ni = 0; ni < 4; ++ni) {
      int col = bn + wn + ni * 16 + lm;
      float bc = bias1[col];
#pragma unroll
      for (int r = 0; r < 4; ++r) {
        int row = bm + wm + mi * 16 + q * 4 + r;
        osum[(long)row * 2048 + col] = ov[mi][ni][r] + siluf(acc[mi][ni][r] + bc);
      }
    }
}

// ---------------- fused: sh = wig_node @ osum; z = 2(xs+xt)+asum+pad(sh); msg = wigner @ z ------------
// 512 threads / edge. Split-bf16 (hi/lo, 3 products) keeps fp32-equivalent accuracy.
__global__ __launch_bounds__(512, 4) void rotate_msg_fused_kernel(
    const float* __restrict__ x, const float* __restrict__ wigner,
    const int* __restrict__ eidx, const float* __restrict__ asum,
    const float* __restrict__ osum, const float* __restrict__ wig_node,
    bf16* __restrict__ msg) {
  __shared__ bf16 Ah[48 * 64], Al[48 * 64];        // wigner hi/lo, XOR-swizzled rows (12 KB)
  __shared__ bf16 zTh[128 * 64], zTl[128 * 64];    // z^T hi/lo, GEMM-B layout (32 KB)
  __shared__ float z[49 * 132];                    // fp32 z (25.9 KB)
  __shared__ float osum_s[16 * 128];               // (8 KB)
  __shared__ float wig[256];
  __shared__ float as_s[49];
  const int e = blockIdx.x, tid = threadIdx.x;
  const int s = eidx[e], d = eidx[EE + e];
  const int w = tid >> 6, lane = tid & 63;
  const int lm = lane & 15, q = lane >> 4;

  // ---- P1: stage everything (independent vector loads) ----
  if (tid < 49) as_s[tid] = asum[e * 64 + tid];
  if (tid >= 64 && tid < 128) {
    int i = tid - 64;
    *(float4*)&wig[i * 4] = *(const float4*)&wig_node[(long)e * 256 + i * 4];
  }
  *(float4*)&osum_s[tid * 4] = *(const float4*)&osum[(long)e * 2048 + tid * 4];
  for (int i = tid; i < 48 * 15; i += 512) {  // A zero-pad k in [49,64)
    int m = i / 15, k = 49 + (i - m * 15);
    int off = m * 64 + (((k >> 3) ^ (m & 7)) << 3) + (k & 7);
    Ah[off] = f2b(0.f); Al[off] = f2b(0.f);
  }
  for (int i4 = tid; i4 < 588; i4 += 512) {   // wigner -> Ah/Al (float4 loads)
    float4 v4 = *(const float4*)&wigner[(long)e * 2352 + i4 * 4];
    int i = i4 * 4;
    int m = i / 49, k = i - m * 49;
    float vv[4] = {v4.x, v4.y, v4.z, v4.w};
#pragma unroll
    for (int j = 0; j < 4; ++j) {
      bf16 h = f2b(vv[j]);
      bf16 l = f2b(vv[j] - __bfloat162float(h));
      int off = m * 64 + (((k >> 3) ^ (m & 7)) << 3) + (k & 7);
      Ah[off] = h; Al[off] = l;
      if (++k == 49) { k = 0; ++m; }
    }
  }
  __syncthreads();

  // ---- P2: z build (float4 writes, conflict-free), sh fused inline for rows l<16 ----
  {
    const float* xs = x + (long)s * (LL * CC);
    const float* xt = x + (long)d * (LL * CC);
    for (int i4 = tid; i4 < 49 * 32; i4 += 512) {
      int l = i4 >> 5, c4 = i4 & 31;
      float4 a = *(const float4*)&xs[l * 128 + c4 * 4];
      float4 b = *(const float4*)&xt[l * 128 + c4 * 4];
      float ad = as_s[l];
      float4 v;
      v.x = 2.f * (a.x + b.x) + ad;
      v.y = 2.f * (a.y + b.y) + ad;
      v.z = 2.f * (a.z + b.z) + ad;
      v.w = 2.f * (a.w + b.w) + ad;
      if (l < 16) {
#pragma unroll
        for (int j = 0; j < 16; ++j) {
          float wv = wig[l * 16 + j];                       // broadcast
          float4 o = *(const float4*)&osum_s[j * 128 + c4 * 4];
          v.x += wv * o.x; v.y += wv * o.y; v.z += wv * o.z; v.w += wv * o.w;
        }
      }
      *(float4*)&z[l * 132 + c4 * 4] = v;
    }
  }
  __syncthreads();

  // ---- P3: transpose via 4x float4 reads (conflict-free granule map) + 8B packed writes (2-way) ----
  {
    const int b0 = (tid & 15) * 4;
    const int c0 = (tid >> 4) * 4;
    float4 rv[4];
#pragma unroll
    for (int j = 0; j < 4; ++j)
      rv[j] = (b0 + j < 49) ? *(const float4*)&z[(b0 + j) * 132 + c0]
                            : (float4){0.f, 0.f, 0.f, 0.f};
#pragma unroll
    for (int i = 0; i < 4; ++i) {
      int c = c0 + i;
      union { bf16 b[4]; unsigned long long u; } hu, lu;
#pragma unroll
      for (int j = 0; j < 4; ++j) {
        float v = getc(rv[j], i);
        bf16 h = f2b(v);
        hu.b[j] = h;
        lu.b[j] = f2b(v - __bfloat162float(h));
      }
      int off = c * 64 + (((b0 >> 3) ^ (c & 7)) << 3) + (b0 & 7);
      *(unsigned long long*)&zTh[off] = hu.u;
      *(unsigned long long*)&zTl[off] = lu.u;
    }
  }
  __syncthreads();

  // ---- P4: MFMA (wave w -> n-tile w, m-tiles = NY taps) + store ----
  short8 ah[3][2], alo[3][2], bh[2], bl[2];
#pragma unroll
  for (int mi = 0; mi < 3; ++mi)
#pragma unroll
    for (int ks = 0; ks < 2; ++ks) {
      int off = (mi * 16 + lm) * 64 + (((ks * 4 + q) ^ (lm & 7)) << 3);
      ah[mi][ks] = *(const short8*)&Ah[off];
      alo[mi][ks] = *(const short8*)&Al[off];
    }
#pragma unroll
  for (int ks = 0; ks < 2; ++ks) {
    int off = (w * 16 + lm) * 64 + (((ks * 4 + q) ^ (lm & 7)) << 3);
    bh[ks] = *(const short8*)&zTh[off];
    bl[ks] = *(const short8*)&zTl[off];
  }
  f32x4 acc[3];
#pragma unroll
  for (int mi = 0; mi < 3; ++mi) acc[mi] = (f32x4){0.f, 0.f, 0.f, 0.f};
#pragma unroll
  for (int mi = 0; mi < 3; ++mi)
#pragma unroll
    for (int ks = 0; ks < 2; ++ks) {
      acc[mi] = __builtin_amdgcn_mfma_f32_16x16x32_bf16(ah[mi][ks], bh[ks], acc[mi], 0, 0, 0);
      acc[mi] = __builtin_amdgcn_mfma_f32_16x16x32_bf16(ah[mi][ks], bl[ks], acc[mi], 0, 0, 0);
      acc[mi] = __builtin_amdgcn_mfma_f32_16x16x32_bf16(alo[mi][ks], bh[ks], acc[mi], 0, 0, 0);
    }
  {
    int c = w * 16 + lm;
#pragma unroll
    for (int mi = 0; mi < 3; ++mi) {
      long base = ((long)e * 3 + mi) * 2048 + c;
#pragma unroll
      for (int r = 0; r < 4; ++r)
        msg[base + (q * 4 + r) * 128] = f2b(acc[mi][r]);
    }
  }
}

// ---------------- m2mean: mr[e][nc][c] = mean_ny silu(m1[e,ny] @ Wp2 + bp2), one-shot per block --------
// grid (EE/16, 16): 16 edges (48 m1 rows) x one 128-col N-chunk (nc). 256 threads, no loop, no prefetch.
__global__ __launch_bounds__(256) void m2mean_kernel(
    const bf16* __restrict__ m1, const bf16* __restrict__ BTp2,
    const float* __restrict__ bp2, float* __restrict__ mr) {
  __shared__ short As2[2][48 * 64];    // 12 KB
  __shared__ short Bs2[2][128 * 64];   // 32 KB
  __shared__ float pbuf[48 * 132];     // 25.3 KB
  const int tid = threadIdx.x;
  const int w = tid >> 6, lane = tid & 63;
  const int lm = lane & 15, q = lane >> 4;
  const int e0 = blockIdx.x * 16, nc = blockIdx.y;

  // stage A: 48 m1 rows (16 edges x 3 ny), 3 uint4/thread
#pragma unroll
  for (int it = 0; it < 3; ++it) {
    int lc = it * 256 + tid;
    int m = lc >> 4, k8 = lc & 15;
    uint4 v = *(const uint4*)((const char*)m1 + ((long)(e0 * 3 + m) * 128 + k8 * 8) * 2);
    *(uint4*)&As2[k8 >> 3][(m * 8 + ((k8 & 7) ^ (m & 7))) * 8] = v;
  }
  // stage B chunk: rows nc*128 .. nc*128+128 of BTp2, 8 uint4/thread
#pragma unroll
  for (int it = 0; it < 8; ++it) {
    int lc = it * 256 + tid;
    int n = lc >> 4, k8 = lc & 15;
    uint4 v = *(const uint4*)((const char*)BTp2 + ((long)(nc * 128 + n) * 128 + k8 * 8) * 2);
    *(uint4*)&Bs2[k8 >> 3][(n * 8 + ((k8 & 7) ^ (n & 7))) * 8] = v;
  }
  __syncthreads();

  // MFMA: wave w -> n-tiles {2w, 2w+1}; m-tiles 0..2; K=128 (4 k-steps)
  f32x4 acc[3][2];
#pragma unroll
  for (int mi = 0; mi < 3; ++mi)
#pragma unroll
    for (int j = 0; j < 2; ++j) acc[mi][j] = (f32x4){0.f, 0.f, 0.f, 0.f};
#pragma unroll
  for (int ks = 0; ks < 4; ++ks) {
    int kh = ks >> 1, ksl = ks & 1;
    short8 af[3], bfr[2];
#pragma unroll
    for (int mi = 0; mi < 3; ++mi) {
      int row = mi * 16 + lm;
      af[mi] = *(const short8*)&As2[kh][(row * 8 + ((ksl * 4 + q) ^ (row & 7))) * 8];
    }
#pragma unroll
    for (int j = 0; j < 2; ++j) {
      int row = (w * 2 + j) * 16 + lm;
      bfr[j] = *(const short8*)&Bs2[kh][(row * 8 + ((ksl * 4 + q) ^ (row & 7))) * 8];
    }
#pragma unroll
    for (int mi = 0; mi < 3; ++mi)
#pragma unroll
      for (int j = 0; j < 2; ++j)
        acc[mi][j] = __builtin_amdgcn_mfma_f32_16x16x32_bf16(af[mi], bfr[j], acc[mi][j], 0, 0, 0);
  }
  // silu + bias -> pbuf
#pragma unroll
  for (int mi = 0; mi < 3; ++mi)
#pragma unroll
    for (int j = 0; j < 2; ++j) {
      int col = (w * 2 + j) * 16 + lm;
      float bc = bp2[nc * 128 + col];
#pragma unroll
      for (int r = 0; r < 4; ++r)
        pbuf[(mi * 16 + q * 4 + r) * 132 + col] = siluf(acc[mi][j][r] + bc);
    }
  __syncthreads();
  // mean over ny (3 consecutive rows) -> mr[e][nc*128 + c]
#pragma unroll
  for (int it = 0; it < 8; ++it) {
    int idx = it * 256 + tid;
    int el = idx >> 7, c = idx & 127;
    float mv = (pbuf[(3 * el + 0) * 132 + c] + pbuf[(3 * el + 1) * 132 + c] +
                pbuf[(3 * el + 2) * 132 + c]) * (1.f / 3.f);
    mr[(long)(e0 + el) * 2048 + nc * 128 + c] = mv;
  }
}

// ---------------- rot_out: out[e] = inv_sqrt3 * wigner_inv[e] @ mr[e], 4 edges/block ----------------
__global__ __launch_bounds__(512) void rot_out_kernel(
    const float* __restrict__ mr, const float* __restrict__ wigner_inv,
    float* __restrict__ out) {
  __shared__ float mr_s[4 * 2048];     // 32 KB
  __shared__ float wv_s[4 * 784];      // 12.5 KB
  const int tid = threadIdx.x;
  const int e0 = blockIdx.x * 4;
  for (int i4 = tid; i4 < 2048; i4 += 512)
    *(float4*)&mr_s[i4 * 4] = *(const float4*)&mr[(long)e0 * 2048 + i4 * 4];
  for (int i4 = tid; i4 < 784; i4 += 512)
    *(float4*)&wv_s[i4 * 4] = *(const float4*)&wigner_inv[(long)e0 * 784 + i4 * 4];
  __syncthreads();
  {
    const int c4 = tid & 31, sb = (tid >> 5) & 3, ep = tid >> 7;
#pragma unroll 1
    for (int bb = 0; bb < 13; ++bb) {
      int b = bb * 4 + sb;
      if (b < 49) {
        float a0 = 0.f, a1 = 0.f, a2 = 0.f, a3 = 0.f;
#pragma unroll
        for (int r = 0; r < 16; ++r) {
          float wvv = wv_s[ep * 784 + b * 16 + r];
          const float4 m = *(const float4*)&mr_s[ep * 2048 + r * 128 + c4 * 4];
          a0 += wvv * m.x; a1 += wvv * m.y; a2 += wvv * m.z; a3 += wvv * m.w;
        }
        float4 o;
        o.x = a0 * 0.57735026918962576f; o.y = a1 * 0.57735026918962576f;
        o.z = a2 * 0.57735026918962576f; o.w = a3 * 0.57735026918962576f;
        *(float4*)&out[(long)(e0 + ep) * 6272 + b * 128 + c4 * 4] = o;
      }
    }
  }
}

// ---------------- host side ----------------
extern "C" void kernel_launch(void* const* d_in, const int* in_sizes, int n_in,
                              void* d_out, int out_size, void* d_ws, size_t ws_size,
                              hipStream_t stream) {
  (void)in_sizes; (void)n_in; (void)out_size; (void)ws_size;
  const float* x        = (const float*)d_in[0];
  const float* x_glovec = (const float*)d_in[2];
  const float* x_edge   = (const float*)d_in[3];
  const int*   eidx     = (const int*)d_in[4];
  const float* W_cg1   = (const float*)d_in[8];
  const float* W_cg21  = (const float*)d_in[9];
  const float* W_cg22  = (const float*)d_in[10];
  const float* Wn1a = (const float*)d_in[11];
  const float* bn1a = (const float*)d_in[12];
  const float* Wn1b = (const float*)d_in[13];
  const float* bn1b = (const float*)d_in[14];
  const float* Wn2a = (const float*)d_in[15];
  const float* bn2a = (const float*)d_in[16];
  const float* Wn2b = (const float*)d_in[17];
  const float* bn2b = (const float*)d_in[18];
  const float* Wd   = (const float*)d_in[19];
  const float* bd   = (const float*)d_in[20];
  const float* Wp1  = (const float*)d_in[21];
  const float* bp1  = (const float*)d_in[22];
  const float* Wp2  = (const float*)d_in[23];
  const float* bp2  = (const float*)d_in[24];
  const float* wigner     = (const float*)d_in[25];
  const float* wigner_inv = (const float*)d_in[26];
  const float* wig_node   = (const float*)d_in[27];

  char* W = (char*)d_ws;
  bf16*  featst = (bf16*)(W + 0);            // 8192 x 2112 bf16 (34.6 MB)
  float* p_osum = (float*)(W + 34603008);    // 4096 x 2048 f32 (33.5 MB)
  float* p_mr   = (float*)(W + 68157440);    // 4096 x 2048 f32 (33.5 MB) for mean_ny(silu(m2))
  bf16*  msg    = (bf16*)(W + 135266304);    // 12288 x 2048 bf16 (50.3 MB)
  bf16*  hstack = (bf16*)(W + 185597952);    // 8192 x 128 bf16
  bf16*  m1     = (bf16*)(W + 187695104);    // 12288 x 128 bf16
  float* p_xe   = (float*)(W + 190840832);   // 4096 x 128 f32
  float* p_xmean= (float*)(W + 192937984);   // 100352 f32
  bf16*  BTa    = (bf16*)(W + 194142208);    // 2 x 128 x 2112
  bf16*  BTb    = (bf16*)(W + 195223552);    // 2 x 2048 x 128
  bf16*  BTp1   = (bf16*)(W + 196272128);    // 128 x 2048
  bf16*  BTp2   = (bf16*)(W + 196796416);    // 2048 x 128 (ends 197320704)
  float* p_asum = (float*)(W + 197320704);   // 4096 x 64 f32 (1 MB)
  float* p_mid  = (float*)(W + 198369280);   // 4096 x 32 f32 (512 KB)
  bf16*  BT1    = (bf16*)(W + 198893568);    // 32 x 2432 bf16 (152 KB)
  bf16*  BT2    = (bf16*)(W + 199049216);    // 64 x 2496 bf16 (312 KB; ends 199368704)

  TJobs tj;
  tj.j[0] = {Wn1a, BTa,            2064, 128, 2112};
  tj.j[1] = {Wn2a, BTa + 270336,   2064, 128, 2112};
  tj.j[2] = {Wn1b, BTb,            128, 2048, 128};
  tj.j[3] = {Wn2b, BTb + 262144,   128, 2048, 128};
  tj.j[4] = {Wp1,  BTp1,           2048, 128, 2048};
  tj.j[5] = {Wp2,  BTp2,           128, 2048, 128};
  transpose_cvt_kernel<<<dim3(1056, 6), 256, 0, stream>>>(tj);
  cg_prep_kernel<<<dim3(624, 2), 256, 0, stream>>>(W_cg1, W_cg21, W_cg22, BT1, BT2);

  node_mean_kernel<<<(NN * LL) / 4, 256, 0, stream>>>(x, p_xmean);
  // CG bilinears: A generated on the fly inside the GEMM (no P1/P2 materialization)
  cg1_kernel<<<EE / 32, 256, 0, stream>>>(p_xmean, eidx, BT1, p_mid);
  cg2_kernel<<<EE / 32, 256, 0, stream>>>(p_xmean, p_mid, eidx, BT2, p_asum);

  gemm_f32_silu<<<dim3(EE / 64, 2), 256, 0, stream>>>(x_edge, Wd, bd, p_xe, EE, HH, 128);
  build_feat_kernel<<<EE, 256, 0, stream>>>(x, x_glovec, wig_node, eidx, featst);
  // h = silu(feat @ Wna): M=8192, N=128, K=2112, stacked weights (BM=32 -> 256 blocks)
  gemm_mfma<32, true, false, true><<<dim3(256, 1), 256, 0, stream>>>(
      featst, BTa, BTa + 270336, bn1a, bn2a, nullptr, hstack, 8192, 128, 2112, 4096);
  // osum = silu(h1 @ Wn1b + b1) + silu(h2 @ Wn2b + b2): M=4096, N=2048, K=128
  gemm_osum<<<dim3(32, 16), 256, 0, stream>>>(hstack, BTb, BTb + 262144, bn1b, bn2b, p_osum);
  // fused rotback + z-build + msg GEMM
  rotate_msg_fused_kernel<<<EE, 512, 0, stream>>>(
      x, wigner, eidx, p_asum, p_osum, wig_node, msg);
  // m1 = silu(msg @ Wp1) * xe: M=12288, N=128, K=2048, bf16 out (BM=32 -> 384 blocks)
  gemm_mfma<32, true, true, true><<<dim3(384, 1), 256, 0, stream>>>(
      msg, BTp1, BTp1, bp1, bp1, p_xe, m1, 12288, 128, 2048, 1 << 30);
  // m2-path split: one-shot mean GEMM (4096 blocks) + streaming rotation
  m2mean_kernel<<<dim3(EE / 16, 16), 256, 0, stream>>>(m1, BTp2, bp2, p_mr);
  rot_out_kernel<<<EE / 4, 512, 0, stream>>>(p_mr, wigner_inv, (float*)d_out);
}

// Round 8
// 509.902 us; speedup vs baseline: 1.2875x; 1.0685x over previous
//
#include <hip/hip_runtime.h>
#include <hip/hip_bf16.h>

typedef __hip_bfloat16 bf16;
typedef __attribute__((ext_vector_type(8))) short short8;
typedef __attribute__((ext_vector_type(4))) float f32x4;

#define NN 2048
#define EE 4096
#define LL 49
#define LRR 16
#define NYY 3
#define CC 128
#define HH 128

#define K1P 2432   // 2401 padded to x64 (BT1 K); K-split halves of 1216
#define K2P 2496   // 2450 padded to x64 (BT2 K); K-split halves of 1248

__device__ __forceinline__ float siluf(float v) { return v * (1.0f / (1.0f + __expf(-v))); }
__device__ __forceinline__ bf16 f2b(float v) { return __float2bfloat16(v); }
__device__ __forceinline__ float getc(float4 v, int i) {
  return i == 0 ? v.x : i == 1 ? v.y : i == 2 ? v.z : v.w;
}

// ---------------- weight convert + transpose: out[n*Kp+k] = bf16(in[k*N+n]), zero-pad k>=K ----------------
struct TJob { const float* in; bf16* out; int K, N, Kp; };
struct TJobs { TJob j[6]; };

__global__ __launch_bounds__(256) void transpose_cvt_kernel(TJobs jobs) {
  TJob jb = jobs.j[blockIdx.y];
  int i = blockIdx.x * 256 + threadIdx.x;
  if (i < jb.N * jb.Kp) {
    int n = i / jb.Kp, k = i - n * jb.Kp;
    jb.out[i] = (k < jb.K) ? f2b(jb.in[(long)k * jb.N + n]) : f2b(0.f);
  }
}

// ---------------- CG weight prep: BT1[32][K1P], BT2[64][K2P] (transposed, bf16, zero-padded) ----------------
__global__ __launch_bounds__(256) void cg_prep_kernel(
    const float* __restrict__ Wcg1, const float* __restrict__ Wcg21,
    const float* __restrict__ Wcg22, bf16* __restrict__ BT1, bf16* __restrict__ BT2) {
  int i = blockIdx.x * 256 + threadIdx.x;
  if (blockIdx.y == 0) {
    if (i < 32 * K1P) {
      int o = i / K1P, k = i - o * K1P;
      float v = (o < 25 && k < 2401) ? Wcg1[k * 25 + o] : 0.f;
      BT1[i] = f2b(v);
    }
  } else {
    if (i < 64 * K2P) {
      int o = i / K2P, k = i - o * K2P;
      float v = 0.f;
      if (o < 49) {
        if (k < 1225) v = Wcg21[k * 49 + o];
        else if (k < 2450) v = Wcg22[(k - 1225) * 49 + o];
      }
      BT2[i] = f2b(v);
    }
  }
}

// ---------------- per-node channel mean ----------------
__global__ __launch_bounds__(256) void node_mean_kernel(const float* __restrict__ x,
                                                        float* __restrict__ xmean) {
  int row = blockIdx.x * 4 + (threadIdx.x >> 6);
  int lane = threadIdx.x & 63;
  const float* p = x + (long)row * CC;
  float s = p[lane] + p[lane + 64];
  for (int off = 32; off > 0; off >>= 1) s += __shfl_down(s, off);
  if (lane == 0) xmean[row] = s * (1.0f / 128.0f);
}

// ---------------- cg1: mid_part[half][e][o] = (xm_e (x) ym_e) @ BT1^T over K-half, A on the fly --------
// 32 edges/block, K-split x2 via blockIdx.y (19 iters each). grid (128,2) x 256 threads.
__global__ __launch_bounds__(256) void cg1_kernel(
    const float* __restrict__ xmean, const int* __restrict__ eidx,
    const bf16* __restrict__ BT1, float* __restrict__ mid_part) {
  __shared__ float sxm[32 * 49], sym[32 * 49];
  __shared__ bf16 As[32 * 64];
  __shared__ bf16 Bs[32 * 64];
  __shared__ int se[32], de[32];
  const int tid = threadIdx.x, w = tid >> 6, lane = tid & 63;
  const int lm = lane & 15, q = lane >> 4;
  const int e0 = blockIdx.x * 32;
  const int koff = blockIdx.y * 1216;
  float* out = mid_part + (long)blockIdx.y * (EE * 32);
  if (tid < 32) { se[tid] = eidx[e0 + tid]; de[tid] = eidx[EE + e0 + tid]; }
  __syncthreads();
  for (int i = tid; i < 32 * 49; i += 256) {
    int m = i / 49, l = i - m * 49;
    sxm[i] = xmean[se[m] * 49 + l];
    sym[i] = xmean[de[m] * 49 + l];
  }
  const int mi = w >> 1, ni = w & 1;
  f32x4 acc = (f32x4){0.f, 0.f, 0.f, 0.f};
  for (int k0 = koff; k0 < koff + 1216; k0 += 64) {
    __syncthreads();
    // generate A tile: As[m][kk] = xm[m][i]*ym[m][j], k=k0+kk=i*49+j
    for (int idx = tid; idx < 2048; idx += 256) {
      int m = idx >> 6, kk = idx & 63;
      int k = k0 + kk;
      float v = 0.f;
      if (k < 2401) { int i = k / 49, j = k - i * 49; v = sxm[m * 49 + i] * sym[m * 49 + j]; }
      int k8 = kk >> 3;
      As[(m * 8 + (k8 ^ (m & 7))) * 8 + (kk & 7)] = f2b(v);
    }
    {  // stage B tile (1 uint4/thread)
      int n = tid >> 3, k8 = tid & 7;
      uint4 v = *(const uint4*)((const char*)BT1 + ((long)n * K1P + k0 + k8 * 8) * 2);
      *(uint4*)&Bs[(n * 8 + (k8 ^ (n & 7))) * 8] = v;
    }
    __syncthreads();
#pragma unroll
    for (int ks = 0; ks < 2; ++ks) {
      int am = mi * 16 + lm, bn = ni * 16 + lm;
      short8 af = *(const short8*)&As[(am * 8 + ((ks * 4 + q) ^ (am & 7))) * 8];
      short8 bfr = *(const short8*)&Bs[(bn * 8 + ((ks * 4 + q) ^ (bn & 7))) * 8];
      acc = __builtin_amdgcn_mfma_f32_16x16x32_bf16(af, bfr, acc, 0, 0, 0);
    }
  }
#pragma unroll
  for (int r = 0; r < 4; ++r)
    out[(long)(e0 + mi * 16 + q * 4 + r) * 32 + ni * 16 + lm] = acc[r];
}

// ---------------- cg2: asum_part[half][e][o] = [xm (x) mid | ym (x) mid] @ BT2^T over K-half ----------
// 32 edges/block, K-split x2 via blockIdx.y (19-20 iters each). grid (128,2) x 256 threads.
__global__ __launch_bounds__(256) void cg2_kernel(
    const float* __restrict__ xmean, const float* __restrict__ mid0,
    const float* __restrict__ mid1, const int* __restrict__ eidx,
    const bf16* __restrict__ BT2, float* __restrict__ asum0, float* __restrict__ asum1) {
  __shared__ float sxm[32 * 49], sym[32 * 49], smid[32 * 25];
  __shared__ bf16 As[32 * 64];
  __shared__ bf16 Bs[64 * 64];
  __shared__ int se[32], de[32];
  const int tid = threadIdx.x, w = tid >> 6, lane = tid & 63;
  const int lm = lane & 15, q = lane >> 4;
  const int e0 = blockIdx.x * 32;
  const int koff = blockIdx.y * 1248;
  float* out = blockIdx.y ? asum1 : asum0;
  if (tid < 32) { se[tid] = eidx[e0 + tid]; de[tid] = eidx[EE + e0 + tid]; }
  __syncthreads();
  for (int i = tid; i < 32 * 49; i += 256) {
    int m = i / 49, l = i - m * 49;
    sxm[i] = xmean[se[m] * 49 + l];
    sym[i] = xmean[de[m] * 49 + l];
  }
  for (int i = tid; i < 32 * 25; i += 256) {
    int m = i / 25, l = i - m * 25;
    long idx = (long)(e0 + m) * 32 + l;
    smid[i] = mid0[idx] + mid1[idx];
  }
  const int ni = w;
  f32x4 acc[2];
  acc[0] = (f32x4){0.f, 0.f, 0.f, 0.f};
  acc[1] = (f32x4){0.f, 0.f, 0.f, 0.f};
  for (int k0 = koff; k0 < koff + 1248; k0 += 64) {
    __syncthreads();
    for (int idx = tid; idx < 2048; idx += 256) {
      int m = idx >> 6, kk = idx & 63;
      int k = k0 + kk;
      float v = 0.f;
      if (k < 1225) {
        int i = k / 25, mm = k - i * 25;
        v = sxm[m * 49 + i] * smid[m * 25 + mm];
      } else if (k < 2450) {
        int kk2 = k - 1225;
        int i = kk2 / 25, mm = kk2 - i * 25;
        v = sym[m * 49 + i] * smid[m * 25 + mm];
      }
      int k8 = kk >> 3;
      As[(m * 8 + (k8 ^ (m & 7))) * 8 + (kk & 7)] = f2b(v);
    }
#pragma unroll
    for (int it = 0; it < 2; ++it) {  // stage B: 64 rows x 64 k
      int lc = it * 256 + tid;
      int n = lc >> 3, k8 = lc & 7;
      uint4 v = *(const uint4*)((const char*)BT2 + ((long)n * K2P + k0 + k8 * 8) * 2);
      *(uint4*)&Bs[(n * 8 + (k8 ^ (n & 7))) * 8] = v;
    }
    __syncthreads();
#pragma unroll
    for (int ks = 0; ks < 2; ++ks) {
      int bn = ni * 16 + lm;
      short8 bfr = *(const short8*)&Bs[(bn * 8 + ((ks * 4 + q) ^ (bn & 7))) * 8];
#pragma unroll
      for (int mi = 0; mi < 2; ++mi) {
        int am = mi * 16 + lm;
        short8 af = *(const short8*)&As[(am * 8 + ((ks * 4 + q) ^ (am & 7))) * 8];
        acc[mi] = __builtin_amdgcn_mfma_f32_16x16x32_bf16(af, bfr, acc[mi], 0, 0, 0);
      }
    }
  }
#pragma unroll
  for (int mi = 0; mi < 2; ++mi)
#pragma unroll
    for (int r = 0; r < 4; ++r)
      out[(long)(e0 + mi * 16 + q * 4 + r) * 64 + ni * 16 + lm] = acc[mi][r];
}

// ---------------- feat build -> bf16 [8192][2112] (rows e, 4096+e), pad cols 2064..2111 = 0 ----------------
__global__ __launch_bounds__(256) void build_feat_kernel(
    const float* __restrict__ x, const float* __restrict__ x_glovec,
    const float* __restrict__ wig_node, const int* __restrict__ eidx,
    bf16* __restrict__ featst) {
  __shared__ float wig[256];
  __shared__ float xa[2048], xb[2048], tmp[2048];
  int e = blockIdx.x, tid = threadIdx.x;
  int s = eidx[e], d = eidx[EE + e];
  wig[tid] = wig_node[e * 256 + tid];
  if (tid < 48) {
    featst[(long)e * 2112 + 2064 + tid] = f2b(0.f);
    featst[(long)(EE + e) * 2112 + 2064 + tid] = f2b(0.f);
  }
  for (int i4 = tid; i4 < 512; i4 += 256) {
    int l = i4 >> 5, c4 = i4 & 31;
    *(float4*)&xa[l * 128 + c4 * 4] = *(const float4*)&x[((long)s * LL + l) * CC + c4 * 4];
    *(float4*)&xb[l * 128 + c4 * 4] = *(const float4*)&x[((long)d * LL + l) * CC + c4 * 4];
  }
  __syncthreads();
  for (int idx = tid; idx < 2048; idx += 256) {
    int i = idx >> 7, c = idx & 127;
    float a = 0.f;
#pragma unroll
    for (int j = 0; j < 16; ++j) a += wig[j * 16 + i] * xa[j * 128 + c];
    tmp[idx] = a;
    featst[(long)e * 2112 + i * 129 + c] = f2b(a);
  }
  __syncthreads();
  {
    int row = tid >> 4, t = tid & 15;
    float m = 0.f;
#pragma unroll
    for (int k = 0; k < 8; ++k) m += tmp[row * 128 + t + k * 16];
    m += __shfl_down(m, 8, 16);
    m += __shfl_down(m, 4, 16);
    m += __shfl_down(m, 2, 16);
    m += __shfl_down(m, 1, 16);
    if (t == 0)
      featst[(long)e * 2112 + row * 129 + 128] =
          f2b(m * (1.0f / 128.0f) * x_glovec[(long)d * 16 + row]);
  }
  __syncthreads();
  for (int idx = tid; idx < 2048; idx += 256) {
    int i = idx >> 7, c = idx & 127;
    float a = 0.f;
#pragma unroll
    for (int j = 0; j < 16; ++j) a += wig[j * 16 + i] * xb[j * 128 + c];
    tmp[idx] = a;
    featst[(long)(EE + e) * 2112 + i * 129 + c] = f2b(a);
  }
  __syncthreads();
  {
    int row = tid >> 4, t = tid & 15;
    float m = 0.f;
#pragma unroll
    for (int k = 0; k < 8; ++k) m += tmp[row * 128 + t + k * 16];
    m += __shfl_down(m, 8, 16);
    m += __shfl_down(m, 4, 16);
    m += __shfl_down(m, 2, 16);
    m += __shfl_down(m, 1, 16);
    if (t == 0)
      featst[(long)(EE + e) * 2112 + row * 129 + 128] =
          f2b(m * (1.0f / 128.0f) * x_glovec[(long)s * 16 + row]);
  }
}

// ---------------- fp32 tiled GEMM (only for tiny xe GEMM) ----------------
__global__ __launch_bounds__(256) void gemm_f32_silu(
    const float* __restrict__ A, const float* __restrict__ B,
    const float* __restrict__ bias, float* __restrict__ C, int M, int N, int K) {
  __shared__ float As[16][68];
  __shared__ float Bs[16][64];
  const int tid = threadIdx.x;
  const int bm = blockIdx.x * 64, bn = blockIdx.y * 64;
  const int tx = tid & 15, ty = tid >> 4;
  const int ar = tid >> 2, ak = (tid & 3) * 4;
  const int br = tid >> 4, bc = (tid & 15) * 4;
  float acc[4][4] = {};
  const float* Ap = A + (long)(bm + ar) * K + ak;
  const float* Bp = B + (long)br * N + bn + bc;
  for (int k0 = 0; k0 < K; k0 += 16) {
    const float4 av = *(const float4*)(Ap + k0);
    const float4 bv = *(const float4*)(Bp + (long)k0 * N);
    __syncthreads();
    As[ak + 0][ar] = av.x; As[ak + 1][ar] = av.y;
    As[ak + 2][ar] = av.z; As[ak + 3][ar] = av.w;
    *(float4*)&Bs[br][bc] = bv;
    __syncthreads();
#pragma unroll
    for (int k = 0; k < 16; ++k) {
      const float4 a = *(const float4*)&As[k][ty * 4];
      const float4 b = *(const float4*)&Bs[k][tx * 4];
      acc[0][0] += a.x * b.x; acc[0][1] += a.x * b.y; acc[0][2] += a.x * b.z; acc[0][3] += a.x * b.w;
      acc[1][0] += a.y * b.x; acc[1][1] += a.y * b.y; acc[1][2] += a.y * b.z; acc[1][3] += a.y * b.w;
      acc[2][0] += a.z * b.x; acc[2][1] += a.z * b.y; acc[2][2] += a.z * b.z; acc[2][3] += a.z * b.w;
      acc[3][0] += a.w * b.x; acc[3][1] += a.w * b.y; acc[3][2] += a.w * b.z; acc[3][3] += a.w * b.w;
    }
  }
#pragma unroll
  for (int i = 0; i < 4; ++i) {
    int row = bm + ty * 4 + i;
#pragma unroll
    for (int j = 0; j < 4; ++j) {
      int col = bn + tx * 4 + j;
      C[(long)row * N + col] = siluf(acc[i][j] + bias[col]);
    }
  }
}

// ---------------- bf16 MFMA GEMM: C = epi(A[MxK]bf16 @ BT[NxK]bf16^T + bias) ----------------
template <int BM, bool SILU, bool XE, bool OUT_BF16>
__global__ __launch_bounds__(256) void gemm_mfma(
    const bf16* __restrict__ A, const bf16* __restrict__ B0, const bf16* __restrict__ B1,
    const float* __restrict__ bias0, const float* __restrict__ bias1,
    const float* __restrict__ xe, void* __restrict__ Cout,
    int M, int N, int K, int half) {
  constexpr int MI = (BM + 31) / 32;
  __shared__ short As[BM * 64];
  __shared__ short Bs[128 * 64];
  const int tid = threadIdx.x;
  const int w = tid >> 6, lane = tid & 63;
  const int lm = lane & 15, q = lane >> 4;
  const int bm = blockIdx.x * BM, bn = blockIdx.y * 128;
  const int wm = (w & 1) * (BM / 2), wn = (w >> 1) * 64;
  const bf16* Bp = (bm < half) ? B0 : B1;
  const float* bias = (bm < half) ? bias0 : bias1;

  f32x4 acc[MI][4];
#pragma unroll
  for (int mi = 0; mi < MI; ++mi)
#pragma unroll
    for (int ni = 0; ni < 4; ++ni) acc[mi][ni] = (f32x4){0.f, 0.f, 0.f, 0.f};

  for (int k0 = 0; k0 < K; k0 += 64) {
    __syncthreads();
#pragma unroll
    for (int it = 0; it < BM / 32; ++it) {
      int lc = it * 256 + tid;
      int m = lc >> 3, k8 = lc & 7;
      uint4 v = *(const uint4*)((const char*)A + ((long)(bm + m) * K + k0 + k8 * 8) * 2);
      *(uint4*)&As[(m * 8 + (k8 ^ (m & 7))) * 8] = v;
    }
#pragma unroll
    for (int it = 0; it < 4; ++it) {
      int lc = it * 256 + tid;
      int n = lc >> 3, k8 = lc & 7;
      uint4 v = *(const uint4*)((const char*)Bp + ((long)(bn + n) * K + k0 + k8 * 8) * 2);
      *(uint4*)&Bs[(n * 8 + (k8 ^ (n & 7))) * 8] = v;
    }
    __syncthreads();
#pragma unroll
    for (int ks = 0; ks < 2; ++ks) {
      short8 af[MI], bfr[4];
#pragma unroll
      for (int mi = 0; mi < MI; ++mi) {
        int row = wm + mi * 16 + lm;
        af[mi] = *(const short8*)&As[row * 64 + ((ks * 4 + q) ^ (lm & 7)) * 8];
      }
#pragma unroll
      for (int ni = 0; ni < 4; ++ni) {
        int row = wn + ni * 16 + lm;
        bfr[ni] = *(const short8*)&Bs[row * 64 + ((ks * 4 + q) ^ (lm & 7)) * 8];
      }
#pragma unroll
      for (int mi = 0; mi < MI; ++mi)
#pragma unroll
        for (int ni = 0; ni < 4; ++ni)
          acc[mi][ni] = __builtin_amdgcn_mfma_f32_16x16x32_bf16(af[mi], bfr[ni], acc[mi][ni], 0, 0, 0);
    }
  }
#pragma unroll
  for (int mi = 0; mi < MI; ++mi) {
#pragma unroll
    for (int ni = 0; ni < 4; ++ni) {
      int col = bn + wn + ni * 16 + lm;
      float bcol = bias[col];
#pragma unroll
      for (int r = 0; r < 4; ++r) {
        int row = bm + wm + mi * 16 + q * 4 + r;
        float v = acc[mi][ni][r] + bcol;
        if (SILU) v = siluf(v);
        if (XE) v *= xe[(row / 3) * HH + col];
        if (OUT_BF16) ((bf16*)Cout)[(long)row * N + col] = f2b(v);
        else ((float*)Cout)[(long)row * N + col] = v;
      }
    }
  }
}

// ---------------- osum = silu(h1 @ Wn1b + b1) + silu(h2 @ Wn2b + b2): M=4096, N=2048, K=128 ----------------
__global__ __launch_bounds__(256) void gemm_osum(
    const bf16* __restrict__ A, const bf16* __restrict__ B0w, const bf16* __restrict__ B1w,
    const float* __restrict__ bias0, const float* __restrict__ bias1,
    float* __restrict__ osum) {
  __shared__ short As[128 * 64];
  __shared__ short Bs[128 * 64];
  const int tid = threadIdx.x;
  const int w = tid >> 6, lane = tid & 63;
  const int lm = lane & 15, q = lane >> 4;
  const int bm = blockIdx.x * 128, bn = blockIdx.y * 128;
  const int wm = (w & 1) * 64, wn = (w >> 1) * 64;
  f32x4 ov[4][4];
  f32x4 acc[4][4];
#pragma unroll
  for (int mi = 0; mi < 4; ++mi)
#pragma unroll
    for (int ni = 0; ni < 4; ++ni) acc[mi][ni] = (f32x4){0.f, 0.f, 0.f, 0.f};

#pragma unroll 1
  for (int src = 0; src < 2; ++src) {
    const bf16* Ap = A + (long)src * 4096 * 128;
    const bf16* Bp = src ? B1w : B0w;
#pragma unroll 1
    for (int k0 = 0; k0 < 128; k0 += 64) {
      __syncthreads();
#pragma unroll
      for (int it = 0; it < 4; ++it) {
        int lc = it * 256 + tid;
        int m = lc >> 3, k8 = lc & 7;
        uint4 v = *(const uint4*)((const char*)Ap + ((long)(bm + m) * 128 + k0 + k8 * 8) * 2);
        *(uint4*)&As[(m * 8 + (k8 ^ (m & 7))) * 8] = v;
      }
#pragma unroll
      for (int it = 0; it < 4; ++it) {
        int lc = it * 256 + tid;
        int n = lc >> 3, k8 = lc & 7;
        uint4 v = *(const uint4*)((const char*)Bp + ((long)(bn + n) * 128 + k0 + k8 * 8) * 2);
        *(uint4*)&Bs[(n * 8 + (k8 ^ (n & 7))) * 8] = v;
      }
      __syncthreads();
#pragma unroll
      for (int ks = 0; ks < 2; ++ks) {
        short8 af[4], bfr[4];
#pragma unroll
        for (int mi = 0; mi < 4; ++mi)
          af[mi] = *(const short8*)&As[(wm + mi * 16 + lm) * 64 + ((ks * 4 + q) ^ (lm & 7)) * 8];
#pragma unroll
        for (int ni = 0; ni < 4; ++ni)
          bfr[ni] = *(const short8*)&Bs[(wn + ni * 16 + lm) * 64 + ((ks * 4 + q) ^ (lm & 7)) * 8];
#pragma unroll
        for (int mi = 0; mi < 4; ++mi)
#pragma unroll
          for (int ni = 0; ni < 4; ++ni)
            acc[mi][ni] = __builtin_amdgcn_mfma_f32_16x16x32_bf16(af[mi], bfr[ni], acc[mi][ni], 0, 0, 0);
      }
    }
    if (src == 0) {
#pragma unroll
      for (int mi = 0; mi < 4; ++mi)
#pragma unroll
        for (int ni = 0; ni < 4; ++ni) {
          int col = bn + wn + ni * 16 + lm;
          float bc = bias0[col];
#pragma unroll
          for (int r = 0; r < 4; ++r) ov[mi][ni][r] = siluf(acc[mi][ni][r] + bc);
#pragma unroll
          for (int r = 0; r < 4; ++r) acc[mi][ni][r] = 0.f;
        }
    }
  }
#pragma unroll
  for (int mi = 0; mi < 4; ++mi)
#pragma unroll
    for (int ni = 0; ni < 4; ++ni) {
      int col = bn + wn + ni * 16 + lm;
      float bc = bias1[col];
#pragma unroll
      for (int r = 0; r < 4; ++r) {
        int row = bm + wm + mi * 16 + q * 4 + r;
        osum[(long)row * 2048 + col] = ov[mi][ni][r] + siluf(acc[mi][ni][r] + bc);
      }
    }
}

// ---------------- fused: sh = wig_node @ osum; z = 2(xs+xt)+asum+pad(sh); msg = wigner @ z ------------
// 512 threads / edge. Split-bf16 (hi/lo, 3 products) keeps fp32-equivalent accuracy.
// z stored with float4-slot XOR swizzle (slot = c4 ^ ((l>>2)&7)) -> conflict-free transpose reads.
__global__ __launch_bounds__(512, 4) void rotate_msg_fused_kernel(
    const float* __restrict__ x, const float* __restrict__ wigner,
    const int* __restrict__ eidx, const float* __restrict__ asum0,
    const float* __restrict__ asum1, const float* __restrict__ osum,
    const float* __restrict__ wig_node, bf16* __restrict__ msg) {
  __shared__ bf16 Ah[48 * 64], Al[48 * 64];        // wigner hi/lo, XOR-swizzled rows (12 KB)
  __shared__ bf16 zTh[128 * 64], zTl[128 * 64];    // z^T hi/lo, GEMM-B layout (32 KB)
  __shared__ float z[49 * 132];                    // fp32 z, slot-swizzled (25.9 KB)
  __shared__ float osum_s[16 * 128];               // (8 KB)
  __shared__ float wig[256];
  __shared__ float as_s[49];
  const int e = blockIdx.x, tid = threadIdx.x;
  const int s = eidx[e], d = eidx[EE + e];
  const int w = tid >> 6, lane = tid & 63;
  const int lm = lane & 15, q = lane >> 4;

  // ---- P1: stage everything (independent vector loads) ----
  if (tid < 49) as_s[tid] = asum0[e * 64 + tid] + asum1[e * 64 + tid];
  if (tid >= 64 && tid < 128) {
    int i = tid - 64;
    *(float4*)&wig[i * 4] = *(const float4*)&wig_node[(long)e * 256 + i * 4];
  }
  *(float4*)&osum_s[tid * 4] = *(const float4*)&osum[(long)e * 2048 + tid * 4];
  for (int i = tid; i < 48 * 15; i += 512) {  // A zero-pad k in [49,64)
    int m = i / 15, k = 49 + (i - m * 15);
    int off = m * 64 + (((k >> 3) ^ (m & 7)) << 3) + (k & 7);
    Ah[off] = f2b(0.f); Al[off] = f2b(0.f);
  }
  for (int i4 = tid; i4 < 588; i4 += 512) {   // wigner -> Ah/Al (float4 loads)
    float4 v4 = *(const float4*)&wigner[(long)e * 2352 + i4 * 4];
    int i = i4 * 4;
    int m = i / 49, k = i - m * 49;
    float vv[4] = {v4.x, v4.y, v4.z, v4.w};
#pragma unroll
    for (int j = 0; j < 4; ++j) {
      bf16 h = f2b(vv[j]);
      bf16 l = f2b(vv[j] - __bfloat162float(h));
      int off = m * 64 + (((k >> 3) ^ (m & 7)) << 3) + (k & 7);
      Ah[off] = h; Al[off] = l;
      if (++k == 49) { k = 0; ++m; }
    }
  }
  __syncthreads();

  // ---- P2: z build (float4 writes, slot-swizzled), sh fused inline for rows l<16 ----
  {
    const float* xs = x + (long)s * (LL * CC);
    const float* xt = x + (long)d * (LL * CC);
    for (int i4 = tid; i4 < 49 * 32; i4 += 512) {
      int l = i4 >> 5, c4 = i4 & 31;
      float4 a = *(const float4*)&xs[l * 128 + c4 * 4];
      float4 b = *(const float4*)&xt[l * 128 + c4 * 4];
      float ad = as_s[l];
      float4 v;
      v.x = 2.f * (a.x + b.x) + ad;
      v.y = 2.f * (a.y + b.y) + ad;
      v.z = 2.f * (a.z + b.z) + ad;
      v.w = 2.f * (a.w + b.w) + ad;
      if (l < 16) {
#pragma unroll
        for (int j = 0; j < 16; ++j) {
          float wv = wig[l * 16 + j];                       // broadcast
          float4 o = *(const float4*)&osum_s[j * 128 + c4 * 4];
          v.x += wv * o.x; v.y += wv * o.y; v.z += wv * o.z; v.w += wv * o.w;
        }
      }
      *(float4*)&z[l * 132 + ((c4 ^ ((l >> 2) & 7)) << 2)] = v;
    }
  }
  __syncthreads();

  // ---- P3: transpose via 4x float4 reads (bank map 16(i&1)+4(c0g^i&7): all 32 banks) + 8B writes ----
  {
    const int b0 = (tid & 15) * 4;
    const int c0g = tid >> 4;          // col group 0..31
    const int c0 = c0g * 4;
    const int f = (b0 >> 2) & 7;       // = (b>>2)&7 for all 4 rows of this tile
    float4 rv[4];
#pragma unroll
    for (int j = 0; j < 4; ++j)
      rv[j] = (b0 + j < 49) ? *(const float4*)&z[(b0 + j) * 132 + ((c0g ^ f) << 2)]
                            : (float4){0.f, 0.f, 0.f, 0.f};
#pragma unroll
    for (int i = 0; i < 4; ++i) {
      int c = c0 + i;
      union { bf16 b[4]; unsigned long long u; } hu, lu;
#pragma unroll
      for (int j = 0; j < 4; ++j) {
        float v = getc(rv[j], i);
        bf16 h = f2b(v);
        hu.b[j] = h;
        lu.b[j] = f2b(v - __bfloat162float(h));
      }
      int off = c * 64 + (((b0 >> 3) ^ (c & 7)) << 3) + (b0 & 7);
      *(unsigned long long*)&zTh[off] = hu.u;
      *(unsigned long long*)&zTl[off] = lu.u;
    }
  }
  __syncthreads();

  // ---- P4: MFMA (wave w -> n-tile w, m-tiles = NY taps) + store ----
  short8 ah[3][2], alo[3][2], bh[2], bl[2];
#pragma unroll
  for (int mi = 0; mi < 3; ++mi)
#pragma unroll
    for (int ks = 0; ks < 2; ++ks) {
      int off = (mi * 16 + lm) * 64 + (((ks * 4 + q) ^ (lm & 7)) << 3);
      ah[mi][ks] = *(const short8*)&Ah[off];
      alo[mi][ks] = *(const short8*)&Al[off];
    }
#pragma unroll
  for (int ks = 0; ks < 2; ++ks) {
    int off = (w * 16 + lm) * 64 + (((ks * 4 + q) ^ (lm & 7)) << 3);
    bh[ks] = *(const short8*)&zTh[off];
    bl[ks] = *(const short8*)&zTl[off];
  }
  f32x4 acc[3];
#pragma unroll
  for (int mi = 0; mi < 3; ++mi) acc[mi] = (f32x4){0.f, 0.f, 0.f, 0.f};
#pragma unroll
  for (int mi = 0; mi < 3; ++mi)
#pragma unroll
    for (int ks = 0; ks < 2; ++ks) {
      acc[mi] = __builtin_amdgcn_mfma_f32_16x16x32_bf16(ah[mi][ks], bh[ks], acc[mi], 0, 0, 0);
      acc[mi] = __builtin_amdgcn_mfma_f32_16x16x32_bf16(ah[mi][ks], bl[ks], acc[mi], 0, 0, 0);
      acc[mi] = __builtin_amdgcn_mfma_f32_16x16x32_bf16(alo[mi][ks], bh[ks], acc[mi], 0, 0, 0);
    }
  {
    int c = w * 16 + lm;
#pragma unroll
    for (int mi = 0; mi < 3; ++mi) {
      long base = ((long)e * 3 + mi) * 2048 + c;
#pragma unroll
      for (int r = 0; r < 4; ++r)
        msg[base + (q * 4 + r) * 128] = f2b(acc[mi][r]);
    }
  }
}

// ---------------- m2mean: mr[e][nc][c] = mean_ny silu(m1[e,ny] @ Wp2 + bp2), one-shot per block --------
// grid (EE/16, 16): 16 edges (48 m1 rows) x one 128-col N-chunk (nc). 256 threads, no loop, no prefetch.
__global__ __launch_bounds__(256) void m2mean_kernel(
    const bf16* __restrict__ m1, const bf16* __restrict__ BTp2,
    const float* __restrict__ bp2, float* __restrict__ mr) {
  __shared__ short As2[2][48 * 64];    // 12 KB
  __shared__ short Bs2[2][128 * 64];   // 32 KB
  __shared__ float pbuf[48 * 132];     // 25.3 KB
  const int tid = threadIdx.x;
  const int w = tid >> 6, lane = tid & 63;
  const int lm = lane & 15, q = lane >> 4;
  const int e0 = blockIdx.x * 16, nc = blockIdx.y;

  // stage A: 48 m1 rows (16 edges x 3 ny), 3 uint4/thread
#pragma unroll
  for (int it = 0; it < 3; ++it) {
    int lc = it * 256 + tid;
    int m = lc >> 4, k8 = lc & 15;
    uint4 v = *(const uint4*)((const char*)m1 + ((long)(e0 * 3 + m) * 128 + k8 * 8) * 2);
    *(uint4*)&As2[k8 >> 3][(m * 8 + ((k8 & 7) ^ (m & 7))) * 8] = v;
  }
  // stage B chunk: rows nc*128 .. nc*128+128 of BTp2, 8 uint4/thread
#pragma unroll
  for (int it = 0; it < 8; ++it) {
    int lc = it * 256 + tid;
    int n = lc >> 4, k8 = lc & 15;
    uint4 v = *(const uint4*)((const char*)BTp2 + ((long)(nc * 128 + n) * 128 + k8 * 8) * 2);
    *(uint4*)&Bs2[k8 >> 3][(n * 8 + ((k8 & 7) ^ (n & 7))) * 8] = v;
  }
  __syncthreads();

  // MFMA: wave w -> n-tiles {2w, 2w+1}; m-tiles 0..2; K=128 (4 k-steps)
  f32x4 acc[3][2];
#pragma unroll
  for (int mi = 0; mi < 3; ++mi)
#pragma unroll
    for (int j = 0; j < 2; ++j) acc[mi][j] = (f32x4){0.f, 0.f, 0.f, 0.f};
#pragma unroll
  for (int ks = 0; ks < 4; ++ks) {
    int kh = ks >> 1, ksl = ks & 1;
    short8 af[3], bfr[2];
#pragma unroll
    for (int mi = 0; mi < 3; ++mi) {
      int row = mi * 16 + lm;
      af[mi] = *(const short8*)&As2[kh][(row * 8 + ((ksl * 4 + q) ^ (row & 7))) * 8];
    }
#pragma unroll
    for (int j = 0; j < 2; ++j) {
      int row = (w * 2 + j) * 16 + lm;
      bfr[j] = *(const short8*)&Bs2[kh][(row * 8 + ((ksl * 4 + q) ^ (row & 7))) * 8];
    }
#pragma unroll
    for (int mi = 0; mi < 3; ++mi)
#pragma unroll
      for (int j = 0; j < 2; ++j)
        acc[mi][j] = __builtin_amdgcn_mfma_f32_16x16x32_bf16(af[mi], bfr[j], acc[mi][j], 0, 0, 0);
  }
  // silu + bias -> pbuf
#pragma unroll
  for (int mi = 0; mi < 3; ++mi)
#pragma unroll
    for (int j = 0; j < 2; ++j) {
      int col = (w * 2 + j) * 16 + lm;
      float bc = bp2[nc * 128 + col];
#pragma unroll
      for (int r = 0; r < 4; ++r)
        pbuf[(mi * 16 + q * 4 + r) * 132 + col] = siluf(acc[mi][j][r] + bc);
    }
  __syncthreads();
  // mean over ny (3 consecutive rows) -> mr[e][nc*128 + c]
#pragma unroll
  for (int it = 0; it < 8; ++it) {
    int idx = it * 256 + tid;
    int el = idx >> 7, c = idx & 127;
    float mv = (pbuf[(3 * el + 0) * 132 + c] + pbuf[(3 * el + 1) * 132 + c] +
                pbuf[(3 * el + 2) * 132 + c]) * (1.f / 3.f);
    mr[(long)(e0 + el) * 2048 + nc * 128 + c] = mv;
  }
}

// ---------------- rot_out: out[e] = inv_sqrt3 * wigner_inv[e] @ mr[e], 2 edges/block (7 blk/CU) ------
__global__ __launch_bounds__(512) void rot_out_kernel(
    const float* __restrict__ mr, const float* __restrict__ wigner_inv,
    float* __restrict__ out) {
  __shared__ float mr_s[2 * 2048];     // 16 KB
  __shared__ float wv_s[2 * 784];      // 6.3 KB
  const int tid = threadIdx.x;
  const int e0 = blockIdx.x * 2;
  for (int i4 = tid; i4 < 1024; i4 += 512)
    *(float4*)&mr_s[i4 * 4] = *(const float4*)&mr[(long)e0 * 2048 + i4 * 4];
  for (int i4 = tid; i4 < 392; i4 += 512)
    *(float4*)&wv_s[i4 * 4] = *(const float4*)&wigner_inv[(long)e0 * 784 + i4 * 4];
  __syncthreads();
  {
    const int ep = tid >> 8, local = tid & 255;
    const int c4 = local & 31, sb = local >> 5;   // 8 b-slices
#pragma unroll 1
    for (int bb = 0; bb < 7; ++bb) {
      int b = bb * 8 + sb;
      if (b < 49) {
        float a0 = 0.f, a1 = 0.f, a2 = 0.f, a3 = 0.f;
#pragma unroll
        for (int r = 0; r < 16; ++r) {
          float wvv = wv_s[ep * 784 + b * 16 + r];
          const float4 m = *(const float4*)&mr_s[ep * 2048 + r * 128 + c4 * 4];
          a0 += wvv * m.x; a1 += wvv * m.y; a2 += wvv * m.z; a3 += wvv * m.w;
        }
        float4 o;
        o.x = a0 * 0.57735026918962576f; o.y = a1 * 0.57735026918962576f;
        o.z = a2 * 0.57735026918962576f; o.w = a3 * 0.57735026918962576f;
        *(float4*)&out[(long)(e0 + ep) * 6272 + b * 128 + c4 * 4] = o;
      }
    }
  }
}

// ---------------- host side ----------------
extern "C" void kernel_launch(void* const* d_in, const int* in_sizes, int n_in,
                              void* d_out, int out_size, void* d_ws, size_t ws_size,
                              hipStream_t stream) {
  (void)in_sizes; (void)n_in; (void)out_size; (void)ws_size;
  const float* x        = (const float*)d_in[0];
  const float* x_glovec = (const float*)d_in[2];
  const float* x_edge   = (const float*)d_in[3];
  const int*   eidx     = (const int*)d_in[4];
  const float* W_cg1   = (const float*)d_in[8];
  const float* W_cg21  = (const float*)d_in[9];
  const float* W_cg22  = (const float*)d_in[10];
  const float* Wn1a = (const float*)d_in[11];
  const float* bn1a = (const float*)d_in[12];
  const float* Wn1b = (const float*)d_in[13];
  const float* bn1b = (const float*)d_in[14];
  const float* Wn2a = (const float*)d_in[15];
  const float* bn2a = (const float*)d_in[16];
  const float* Wn2b = (const float*)d_in[17];
  const float* bn2b = (const float*)d_in[18];
  const float* Wd   = (const float*)d_in[19];
  const float* bd   = (const float*)d_in[20];
  const float* Wp1  = (const float*)d_in[21];
  const float* bp1  = (const float*)d_in[22];
  const float* Wp2  = (const float*)d_in[23];
  const float* bp2  = (const float*)d_in[24];
  const float* wigner     = (const float*)d_in[25];
  const float* wigner_inv = (const float*)d_in[26];
  const float* wig_node   = (const float*)d_in[27];

  char* W = (char*)d_ws;
  bf16*  featst = (bf16*)(W + 0);            // 8192 x 2112 bf16 (34.6 MB)
  float* p_osum = (float*)(W + 34603008);    // 4096 x 2048 f32 (33.5 MB)
  float* p_mr   = (float*)(W + 68157440);    // 4096 x 2048 f32 (33.5 MB)
  bf16*  msg    = (bf16*)(W + 135266304);    // 12288 x 2048 bf16 (50.3 MB)
  bf16*  hstack = (bf16*)(W + 185597952);    // 8192 x 128 bf16 (2 MB)
  float* p_midp = (float*)(W + 185597952);   // alias: 2 x 4096 x 32 f32 (1 MB) - consumed by cg2 before h-gemm
  bf16*  m1     = (bf16*)(W + 187695104);    // 12288 x 128 bf16 (3 MB)
  float* p_asum1= (float*)(W + 187695104);   // alias: 4096 x 64 f32 (1 MB) - consumed by rotate_msg before m1-gemm
  float* p_xe   = (float*)(W + 190840832);   // 4096 x 128 f32
  float* p_xmean= (float*)(W + 192937984);   // 100352 f32
  bf16*  BTa    = (bf16*)(W + 194142208);    // 2 x 128 x 2112
  bf16*  BTb    = (bf16*)(W + 195223552);    // 2 x 2048 x 128
  bf16*  BTp1   = (bf16*)(W + 196272128);    // 128 x 2048
  bf16*  BTp2   = (bf16*)(W + 196796416);    // 2048 x 128 (ends 197320704)
  float* p_asum0= (float*)(W + 197320704);   // 4096 x 64 f32 (1 MB)
  bf16*  BT1    = (bf16*)(W + 198893568);    // 32 x 2432 bf16 (152 KB)
  bf16*  BT2    = (bf16*)(W + 199049216);    // 64 x 2496 bf16 (312 KB; ends 199368704)

  TJobs tj;
  tj.j[0] = {Wn1a, BTa,            2064, 128, 2112};
  tj.j[1] = {Wn2a, BTa + 270336,   2064, 128, 2112};
  tj.j[2] = {Wn1b, BTb,            128, 2048, 128};
  tj.j[3] = {Wn2b, BTb + 262144,   128, 2048, 128};
  tj.j[4] = {Wp1,  BTp1,           2048, 128, 2048};
  tj.j[5] = {Wp2,  BTp2,           128, 2048, 128};
  transpose_cvt_kernel<<<dim3(1056, 6), 256, 0, stream>>>(tj);
  cg_prep_kernel<<<dim3(624, 2), 256, 0, stream>>>(W_cg1, W_cg21, W_cg22, BT1, BT2);

  node_mean_kernel<<<(NN * LL) / 4, 256, 0, stream>>>(x, p_xmean);
  // CG bilinears: A generated on the fly, K-split x2 (partials summed at consumers)
  cg1_kernel<<<dim3(EE / 32, 2), 256, 0, stream>>>(p_xmean, eidx, BT1, p_midp);
  cg2_kernel<<<dim3(EE / 32, 2), 256, 0, stream>>>(
      p_xmean, p_midp, p_midp + (long)EE * 32, eidx, BT2, p_asum0, p_asum1);

  gemm_f32_silu<<<dim3(EE / 64, 2), 256, 0, stream>>>(x_edge, Wd, bd, p_xe, EE, HH, 128);
  build_feat_kernel<<<EE, 256, 0, stream>>>(x, x_glovec, wig_node, eidx, featst);
  // h = silu(feat @ Wna): M=8192, N=128, K=2112, stacked weights (BM=32 -> 256 blocks)
  gemm_mfma<32, true, false, true><<<dim3(256, 1), 256, 0, stream>>>(
      featst, BTa, BTa + 270336, bn1a, bn2a, nullptr, hstack, 8192, 128, 2112, 4096);
  // osum = silu(h1 @ Wn1b + b1) + silu(h2 @ Wn2b + b2): M=4096, N=2048, K=128
  gemm_osum<<<dim3(32, 16), 256, 0, stream>>>(hstack, BTb, BTb + 262144, bn1b, bn2b, p_osum);
  // fused rotback + z-build + msg GEMM (asum = h0 + h1 summed in staging)
  rotate_msg_fused_kernel<<<EE, 512, 0, stream>>>(
      x, wigner, eidx, p_asum0, p_asum1, p_osum, wig_node, msg);
  // m1 = silu(msg @ Wp1) * xe: M=12288, N=128, K=2048, bf16 out (BM=32 -> 384 blocks)
  gemm_mfma<32, true, true, true><<<dim3(384, 1), 256, 0, stream>>>(
      msg, BTp1, BTp1, bp1, bp1, p_xe, m1, 12288, 128, 2048, 1 << 30);
  // m2-path split: one-shot mean GEMM (4096 blocks) + streaming rotation (2048 blocks)
  m2mean_kernel<<<dim3(EE / 16, 16), 256, 0, stream>>>(m1, BTp2, bp2, p_mr);
  rot_out_kernel<<<EE / 2, 512, 0, stream>>>(p_mr, wigner_inv, (float*)d_out);
}